// Round 16
// baseline (60.867 us; speedup 1.0000x reference)
//
#include <hip/hip_runtime.h>
#include <cstdint>

#define B_ 8
#define T_ 2048
#define C_ 1024
#define H_ 64
#define BT_ (B_ * T_)

typedef short short8 __attribute__((ext_vector_type(8)));
typedef short bh4 __attribute__((ext_vector_type(4)));
typedef float f32x4 __attribute__((ext_vector_type(4)));

__device__ inline short f2bf(float f) {
  uint32_t u = __float_as_uint(f);
  u += 0x7fffu + ((u >> 16) & 1u);  // RNE; inputs finite
  return (short)(u >> 16);
}

// async global->LDS, 16B per lane; LDS dest = uniform base + lane*16 (HW rule)
__device__ __forceinline__ void gl_lds16(const void* g, void* l) {
  __builtin_amdgcn_global_load_lds(
      (const __attribute__((address_space(1))) unsigned int*)g,
      (__attribute__((address_space(3))) unsigned int*)l, 16, 0, 0);
}

// ---------------------------------------------------------------------------
// prep_w: Wk/Wq/Wv [1024][64] fp32 -> Wt [192][1024] bf16 (transposed).
// Folded into Wk: score scale 1024^-0.5 AND log2(e) (softmax in log2 domain).
// ---------------------------------------------------------------------------
__global__ __launch_bounds__(256) void prep_w(
    const float* __restrict__ Wk, const float* __restrict__ Wq,
    const float* __restrict__ Wv, short* __restrict__ Wt) {
  __shared__ float wl[64][68];
  const int mat = blockIdx.x >> 4;
  const int kc = blockIdx.x & 15;
  const float* W = (mat == 0) ? Wk : (mat == 1) ? Wq : Wv;
  const float sc = (mat == 0) ? 0.03125f * 1.44269504088896f : 1.0f;
  const int t = threadIdx.x;
  const int k0 = kc * 64;
#pragma unroll
  for (int j = 0; j < 4; ++j) {
    int s = t + 256 * j;
    int kr = s >> 4, cf = s & 15;
    float4 v = *reinterpret_cast<const float4*>(&W[(size_t)(k0 + kr) * H_ + cf * 4]);
    wl[kr][cf * 4 + 0] = v.x; wl[kr][cf * 4 + 1] = v.y;
    wl[kr][cf * 4 + 2] = v.z; wl[kr][cf * 4 + 3] = v.w;
  }
  __syncthreads();
#pragma unroll
  for (int j = 0; j < 2; ++j) {
    int s = t + 256 * j;
    int n = s >> 3, g = s & 7;
    short8 o;
#pragma unroll
    for (int i = 0; i < 8; ++i) o[i] = f2bf(wl[8 * g + i][n] * sc);
    *reinterpret_cast<short8*>(&Wt[(size_t)(mat * 64 + n) * C_ + k0 + 8 * g]) = o;
  }
}

// ---------------------------------------------------------------------------
// proj: m97-style GEMM, tile M=64 x N=192, 256 blocks x 512 thr (8 waves).
// LDS 80KB (xs 2x16KB fp32 + ws 2x24KB bf16) -> 2 blocks/CU = 16 waves/CU
// = 4 waves/SIMD (R15's 2/SIMD still exposed part of each barrier drain).
// W-staging amortized over 64 rows (L2 traffic halved vs M=32). All swizzle
// and fragment algebra identical to the proven version. Wave = (row-group
// rg=w>>1 [16 rows], col-half ch=w&1 [96 cols, 6 acc]).
// ---------------------------------------------------------------------------
__global__ __launch_bounds__(512, 1) void proj_kernel(
    const float* __restrict__ x, const short* __restrict__ Wt,
    short* __restrict__ Kp, short* __restrict__ Qp, short* __restrict__ Vt) {
  __shared__ float xs[2][64 * 64];   // 16KB each: 64 rows x 16 slots(16B)
  __shared__ short ws[2][192 * 64];  // 24KB each
  const int t = threadIdx.x;
  const int w = t >> 6, lane = t & 63;
  const int l15 = lane & 15, lg = lane >> 4;
  const int rg = w >> 1, ch = w & 1;
  const int rowBase = blockIdx.x * 64;

  f32x4 acc[6];
  const f32x4 zf = {0.f, 0.f, 0.f, 0.f};
#pragma unroll
  for (int i = 0; i < 6; ++i) acc[i] = zf;

  auto stage = [&](int buf, int k0) {
#pragma unroll
    for (int j = 0; j < 2; ++j) {
      const int seg = w * 2 + j;  // 0..15 (x: 16 segs of 4 rows)
      const int r = seg * 4 + (lane >> 4);
      const float* g =
          &x[(size_t)(rowBase + r) * C_ + k0 + (((lane & 15) ^ (r & 7)) << 2)];
      gl_lds16(g, (char*)&xs[buf][0] + seg * 1024);
    }
#pragma unroll
    for (int j = 0; j < 3; ++j) {
      const int seg = w * 3 + j;  // 0..23 (W: 24 segs of 8 rows)
      const int n = seg * 8 + (lane >> 3);
      const short* g =
          &Wt[(size_t)n * C_ + k0 + (((lane & 7) ^ (n & 7)) << 3)];
      gl_lds16(g, (char*)&ws[buf][0] + seg * 1024);
    }
  };

  stage(0, 0);

#pragma unroll 1
  for (int it = 0; it < 16; ++it) {
    __syncthreads();
    const int cb = it & 1;
    if (it < 15) stage(cb ^ 1, (it + 1) * 64);
    const int arow = 16 * rg + l15;  // 0..63
    const int x7 = arow & 7;
    const float* xrow = &xs[cb][arow * 64];
    float4 fa = *reinterpret_cast<const float4*>(xrow + (((2 * lg) ^ x7) << 2));
    float4 fb = *reinterpret_cast<const float4*>(xrow + (((2 * lg + 1) ^ x7) << 2));
    float4 fc = *reinterpret_cast<const float4*>(xrow + (((2 * lg + 8) ^ x7) << 2));
    float4 fd = *reinterpret_cast<const float4*>(xrow + (((2 * lg + 9) ^ x7) << 2));
    short8 a0, a1;
    a0[0] = f2bf(fa.x); a0[1] = f2bf(fa.y); a0[2] = f2bf(fa.z); a0[3] = f2bf(fa.w);
    a0[4] = f2bf(fb.x); a0[5] = f2bf(fb.y); a0[6] = f2bf(fb.z); a0[7] = f2bf(fb.w);
    a1[0] = f2bf(fc.x); a1[1] = f2bf(fc.y); a1[2] = f2bf(fc.z); a1[3] = f2bf(fc.w);
    a1[4] = f2bf(fd.x); a1[5] = f2bf(fd.y); a1[6] = f2bf(fd.z); a1[7] = f2bf(fd.w);
#pragma unroll
    for (int nt = 0; nt < 6; ++nt) {
      const int n2 = 16 * (6 * ch + nt) + l15, n7 = n2 & 7;
      const short* wrow = &ws[cb][n2 * 64];
      short8 b0 = *reinterpret_cast<const short8*>(wrow + ((lg ^ n7) << 3));
      short8 b1 = *reinterpret_cast<const short8*>(wrow + (((4 + lg) ^ n7) << 3));
      acc[nt] = __builtin_amdgcn_mfma_f32_16x16x32_bf16(a0, b0, acc[nt], 0, 0, 0);
      acc[nt] = __builtin_amdgcn_mfma_f32_16x16x32_bf16(a1, b1, acc[nt], 0, 0, 0);
    }
  }

  // ---- epilogue ----
  const int strip = blockIdx.x * 4 + rg;  // 16-row strip id, 0..1023
  const int rb = strip * 16;
#pragma unroll
  for (int nt = 0; nt < 6; ++nt) {
    const int ntg = 6 * ch + nt;  // global col-tile 0..11
    if (ntg < 8) {                // K (0-3) and Q (4-7) row-major stores
      short* O = (ntg < 4) ? Kp : Qp;
      const int col = (ntg & 3) * 16 + l15;
#pragma unroll
      for (int r = 0; r < 4; ++r)
        O[(size_t)(rb + lg * 4 + r) * H_ + col] = f2bf(acc[nt][r]);
    }
  }
  __syncthreads();  // xs dead; reuse for V transpose
  if (ch == 1) {    // waves 1,3,5,7 hold V tiles (ntg 8..11) for strips rg=0..3
    short* vl = reinterpret_cast<short*>(&xs[0][0]) + rg * (16 * 66);
#pragma unroll
    for (int nt = 2; nt < 6; ++nt)
#pragma unroll
      for (int r = 0; r < 4; ++r)
        vl[(lg * 4 + r) * 66 + (nt - 2) * 16 + l15] = f2bf(acc[nt][r]);
    asm volatile("s_waitcnt lgkmcnt(0)" ::: "memory");
    short8 o0, o1;
#pragma unroll
    for (int i = 0; i < 8; ++i) o0[i] = vl[i * 66 + lane];
#pragma unroll
    for (int i = 0; i < 8; ++i) o1[i] = vl[(8 + i) * 66 + lane];
    const int bb = strip >> 7, tb = (strip & 127) * 16;
    short* dst = &Vt[((size_t)bb * H_ + lane) * T_ + tb];
    *reinterpret_cast<short8*>(dst) = o0;
    *reinterpret_cast<short8*>(dst + 8) = o1;
  }
}

// ---------------------------------------------------------------------------
// attn: R15 verbatim (measured best). 512 blocks x 256 thr (4 waves),
// balanced CU pairing (g=bid>>3; s = g<32 ? 63-g : g-32). Wave = (row-group
// rg=w>>1, k-parity p=w&1). Period = two 64-key K+V tiles staged via
// contiguous global_load_lds, double-buffered (72KB LDS -> 2 blocks/CU).
// Per-lane log2 softmax; 2-way parity combine in dead stage LDS.
// ---------------------------------------------------------------------------
__global__ __launch_bounds__(256) void attn_kernel(
    const short* __restrict__ Kq, const short* __restrict__ Qk,
    const short* __restrict__ Vt, float* __restrict__ out) {
  __shared__ short Ks[4][64 * 64];  // [(per&1)*2 + tile][kv][h]
  __shared__ short Vs[4][64 * 64];  // [same][d][kv]
  __shared__ short Ps[4][16 * 64];  // per-wave P^T staging
  const int t = threadIdx.x, w = t >> 6, lane = t & 63;
  const int l15 = lane & 15, lg = lane >> 4;
  const int batch = blockIdx.x & 7;
  const int g = blockIdx.x >> 3;                 // 0..63
  const int s = (g < 32) ? (63 - g) : (g - 32);  // balanced big/small pairing
  const int p = w & 1;                           // this wave's k-tile parity
  const int rg = w >> 1;                         // row group
  const short* Kb = Kq + (size_t)batch * T_ * H_;
  const short* Qb = Qk + (size_t)batch * T_ * H_;
  const short* Vb = Vt + (size_t)batch * H_ * T_;
  float* ob = out + (size_t)batch * T_ * H_;
  short* ps = &Ps[w][0];
  const f32x4 zf = {0.f, 0.f, 0.f, 0.f};
  const int m7 = (l15 & 7) << 3;
  const int k7 = l15 & 7;

  const int qbase = s * 32;
  const int qrow = qbase + rg * 16 + l15;
  const short8 qa0 = *reinterpret_cast<const short8*>(&Kb[(size_t)qrow * H_ + lg * 8]);
  const short8 qa1 = *reinterpret_cast<const short8*>(&Kb[(size_t)qrow * H_ + lg * 8 + 32]);
  const int nkt = (s >> 1) + 1;    // 64-key tiles
  const int np = (nkt + 1) >> 1;   // periods (2 tiles each)

  const int srow = lane >> 3;
  const int ssw = ((lane & 7) ^ srow) << 3;
  auto stage = [&](int per) {
    int tj = 2 * per + (w >> 1);
    if (tj >= nkt) tj = nkt - 1;
    const int buf = (per & 1) * 2 + (w >> 1);
    const int kbase = tj * 64;
    const int h4 = (w & 1) * 4;
#pragma unroll
    for (int g2 = 0; g2 < 4; ++g2) {
      const int gg = h4 + g2;
      gl_lds16(&Qb[(size_t)(kbase + gg * 8 + srow) * H_ + ssw],
               (char*)&Ks[buf][0] + gg * 1024);
      gl_lds16(&Vb[(size_t)(gg * 8 + srow) * T_ + kbase + ssw],
               (char*)&Vs[buf][0] + gg * 1024);
    }
  };

  f32x4 O[4];
#pragma unroll
  for (int i = 0; i < 4; ++i) O[i] = zf;
  float m = -1e30f, l = 0.f;

  stage(0);

#pragma unroll 1
  for (int j = 0; j < np; ++j) {
    __syncthreads();  // drains staged loads + guards buffer reuse
    if (j + 1 < np) stage(j + 1);
    const int kt = 2 * j + p;
    if (kt < nkt) {
      const int cb = (j & 1) * 2 + p;
      const int kbase = kt * 64;
      f32x4 S[4];
      __builtin_amdgcn_s_setprio(1);
#pragma unroll
      for (int nt = 0; nt < 4; ++nt) {
        S[nt] = zf;
        const short* krow = &Ks[cb][(16 * nt + l15) * 64];
        short8 kf0 = *reinterpret_cast<const short8*>(&krow[(lg ^ k7) << 3]);
        short8 kf1 = *reinterpret_cast<const short8*>(&krow[((4 + lg) ^ k7) << 3]);
        S[nt] = __builtin_amdgcn_mfma_f32_16x16x32_bf16(kf0, qa0, S[nt], 0, 0, 0);
        S[nt] = __builtin_amdgcn_mfma_f32_16x16x32_bf16(kf1, qa1, S[nt], 0, 0, 0);
      }
      __builtin_amdgcn_s_setprio(0);
      if (kt == nkt - 1) {
#pragma unroll
        for (int nt = 0; nt < 4; ++nt) {
          const int klo = kbase + 16 * nt + 4 * lg;
#pragma unroll
          for (int r = 0; r < 4; ++r)
            if (klo + r > qrow) S[nt][r] = -1e30f;
        }
      }
      float mx0 = fmaxf(fmaxf(S[0][0], S[0][1]), fmaxf(S[0][2], S[0][3]));
      float mx1 = fmaxf(fmaxf(S[1][0], S[1][1]), fmaxf(S[1][2], S[1][3]));
      float mx2 = fmaxf(fmaxf(S[2][0], S[2][1]), fmaxf(S[2][2], S[2][3]));
      float mx3 = fmaxf(fmaxf(S[3][0], S[3][1]), fmaxf(S[3][2], S[3][3]));
      float mx = fmaxf(fmaxf(mx0, mx1), fmaxf(mx2, mx3));
      mx = fmaxf(mx, __shfl_xor(mx, 16));
      mx = fmaxf(mx, __shfl_xor(mx, 32));
      const float mn = fmaxf(m, mx);
      const float scv = exp2f(m - mn);
      m = mn;
      float rs = 0.f;
#pragma unroll
      for (int nt = 0; nt < 4; ++nt)
#pragma unroll
        for (int r = 0; r < 4; ++r) {
          const float pv = exp2f(S[nt][r] - mn);
          S[nt][r] = pv;
          rs += pv;
        }
      rs += __shfl_xor(rs, 16);
      rs += __shfl_xor(rs, 32);
      l = l * scv + rs;
#pragma unroll
      for (int nt = 0; nt < 4; ++nt) O[nt] *= scv;
#pragma unroll
      for (int nt = 0; nt < 4; ++nt) {
        bh4 pk;
        pk[0] = f2bf(S[nt][0]); pk[1] = f2bf(S[nt][1]);
        pk[2] = f2bf(S[nt][2]); pk[3] = f2bf(S[nt][3]);
        *reinterpret_cast<bh4*>(&ps[l15 * 64 + ((16 * nt + 4 * lg) ^ m7)]) = pk;
      }
      __builtin_amdgcn_s_setprio(1);
#pragma unroll
      for (int kc = 0; kc < 2; ++kc) {
        const short8 pa = *reinterpret_cast<const short8*>(
            &ps[l15 * 64 + ((32 * kc + 8 * lg) ^ m7)]);
#pragma unroll
        for (int nt = 0; nt < 4; ++nt) {
          const short8 vf = *reinterpret_cast<const short8*>(
              &Vs[cb][(16 * nt + l15) * 64 + (((kc * 4 + lg) ^ k7) << 3)]);
          O[nt] = __builtin_amdgcn_mfma_f32_16x16x32_bf16(vf, pa, O[nt], 0, 0, 0);
        }
      }
      __builtin_amdgcn_s_setprio(0);
    }
  }

  // ---- 2-way parity combine (reuse dead stage LDS) ----
  __syncthreads();
  float* Po = reinterpret_cast<float*>(&Ks[0][0]);   // [4][16][68] f32
  float* Mlp = reinterpret_cast<float*>(&Ps[0][0]);  // [4][16][2]  f32
#pragma unroll
  for (int nt = 0; nt < 4; ++nt)
    *reinterpret_cast<f32x4*>(&Po[(w * 16 + l15) * 68 + 16 * nt + 4 * lg]) = O[nt];
  if (lane < 16) {
    Mlp[(w * 16 + l15) * 2 + 0] = m;
    Mlp[(w * 16 + l15) * 2 + 1] = l;
  }
  __syncthreads();
  {
    const int row = t >> 4, c4 = t & 15;
#pragma unroll
    for (int gg = 0; gg < 2; ++gg) {
      const int s0 = gg * 2, s1 = gg * 2 + 1;
      const float m0 = Mlp[(s0 * 16 + row) * 2], l0 = Mlp[(s0 * 16 + row) * 2 + 1];
      const float m1 = Mlp[(s1 * 16 + row) * 2], l1 = Mlp[(s1 * 16 + row) * 2 + 1];
      const float M = fmaxf(m0, m1);
      const float e0 = exp2f(m0 - M), e1 = exp2f(m1 - M);
      const float L = l0 * e0 + l1 * e1;
      const f32x4 o0 = *reinterpret_cast<const f32x4*>(&Po[(s0 * 16 + row) * 68 + c4 * 4]);
      const f32x4 o1 = *reinterpret_cast<const f32x4*>(&Po[(s1 * 16 + row) * 68 + c4 * 4]);
      const f32x4 res = (o0 * e0 + o1 * e1) * (1.f / L);
      *reinterpret_cast<f32x4*>(&ob[(size_t)(qbase + gg * 16 + row) * H_ + c4 * 4]) = res;
    }
  }
}

extern "C" void kernel_launch(void* const* d_in, const int* in_sizes, int n_in,
                              void* d_out, int out_size, void* d_ws, size_t ws_size,
                              hipStream_t stream) {
  const float* x = (const float*)d_in[0];
  const float* Wk = (const float*)d_in[1];
  const float* Wq = (const float*)d_in[2];
  const float* Wv = (const float*)d_in[3];
  float* out = (float*)d_out;

  short* Kp = (short*)d_ws;                  // [BT][64] bf16 (queries: x@Wk, scale*log2e folded)
  short* Qp = Kp + (size_t)BT_ * H_;         // [BT][64] bf16 (keys:    x@Wq)
  short* Vt = Qp + (size_t)BT_ * H_;         // [8][64][2048] bf16 (values^T)
  short* Wt = Vt + (size_t)BT_ * H_;         // [192][1024] bf16

  hipLaunchKernelGGL(prep_w, dim3(48), dim3(256), 0, stream, Wk, Wq, Wv, Wt);
  hipLaunchKernelGGL(proj_kernel, dim3(256), dim3(512), 0, stream, x, Wt, Kp, Qp, Vt);
  hipLaunchKernelGGL(attn_kernel, dim3(512), dim3(256), 0, stream, Kp, Qp, Vt, out);
}

// Round 17
// 60.011 us; speedup vs baseline: 1.0143x; 1.0143x over previous
//
#include <hip/hip_runtime.h>
#include <cstdint>

#define B_ 8
#define T_ 2048
#define C_ 1024
#define H_ 64
#define BT_ (B_ * T_)

typedef short short8 __attribute__((ext_vector_type(8)));
typedef short bh4 __attribute__((ext_vector_type(4)));
typedef float f32x4 __attribute__((ext_vector_type(4)));

__device__ inline short f2bf(float f) {
  uint32_t u = __float_as_uint(f);
  u += 0x7fffu + ((u >> 16) & 1u);  // RNE; inputs finite
  return (short)(u >> 16);
}

// async global->LDS, 16B per lane; LDS dest = uniform base + lane*16 (HW rule)
__device__ __forceinline__ void gl_lds16(const void* g, void* l) {
  __builtin_amdgcn_global_load_lds(
      (const __attribute__((address_space(1))) unsigned int*)g,
      (__attribute__((address_space(3))) unsigned int*)l, 16, 0, 0);
}

// ---------------------------------------------------------------------------
// prep_w: Wk/Wq/Wv [1024][64] fp32 -> Wt [192][1024] bf16 (transposed).
// Folded into Wk: score scale 1024^-0.5 AND log2(e) (softmax in log2 domain).
// ---------------------------------------------------------------------------
__global__ __launch_bounds__(256) void prep_w(
    const float* __restrict__ Wk, const float* __restrict__ Wq,
    const float* __restrict__ Wv, short* __restrict__ Wt) {
  __shared__ float wl[64][68];
  const int mat = blockIdx.x >> 4;
  const int kc = blockIdx.x & 15;
  const float* W = (mat == 0) ? Wk : (mat == 1) ? Wq : Wv;
  const float sc = (mat == 0) ? 0.03125f * 1.44269504088896f : 1.0f;
  const int t = threadIdx.x;
  const int k0 = kc * 64;
#pragma unroll
  for (int j = 0; j < 4; ++j) {
    int s = t + 256 * j;
    int kr = s >> 4, cf = s & 15;
    float4 v = *reinterpret_cast<const float4*>(&W[(size_t)(k0 + kr) * H_ + cf * 4]);
    wl[kr][cf * 4 + 0] = v.x; wl[kr][cf * 4 + 1] = v.y;
    wl[kr][cf * 4 + 2] = v.z; wl[kr][cf * 4 + 3] = v.w;
  }
  __syncthreads();
#pragma unroll
  for (int j = 0; j < 2; ++j) {
    int s = t + 256 * j;
    int n = s >> 3, g = s & 7;
    short8 o;
#pragma unroll
    for (int i = 0; i < 8; ++i) o[i] = f2bf(wl[8 * g + i][n] * sc);
    *reinterpret_cast<short8*>(&Wt[(size_t)(mat * 64 + n) * C_ + k0 + 8 * g]) = o;
  }
}

// ---------------------------------------------------------------------------
// proj: R15 version verbatim (measured best). 512 blocks x 256 thr (4 waves,
// 2/SIMD). Tile M=32 x N=192, K-step 64, dbuf LDS via global_load_lds.
// Wave = (row-group rg = w>>1 [16 rows], col-half ch = w&1 [96 cols, 6 acc]).
// ---------------------------------------------------------------------------
__global__ __launch_bounds__(256, 1) void proj_kernel(
    const float* __restrict__ x, const short* __restrict__ Wt,
    short* __restrict__ Kp, short* __restrict__ Qp, short* __restrict__ Vt) {
  __shared__ float xs[2][32 * 64];   // 8KB each
  __shared__ short ws[2][192 * 64];  // 24KB each
  const int t = threadIdx.x;
  const int w = t >> 6, lane = t & 63;
  const int l15 = lane & 15, lg = lane >> 4;
  const int rg = w >> 1, ch = w & 1;
  const int rowBase = blockIdx.x * 32;

  f32x4 acc[6];
  const f32x4 zf = {0.f, 0.f, 0.f, 0.f};
#pragma unroll
  for (int i = 0; i < 6; ++i) acc[i] = zf;

  auto stage = [&](int buf, int k0) {
#pragma unroll
    for (int j = 0; j < 2; ++j) {
      const int seg = w * 2 + j;  // 0..7 (x: 8 segs of 4 rows)
      const int r = seg * 4 + (lane >> 4);
      const float* g =
          &x[(size_t)(rowBase + r) * C_ + k0 + (((lane & 15) ^ (r & 7)) << 2)];
      gl_lds16(g, (char*)&xs[buf][0] + seg * 1024);
    }
#pragma unroll
    for (int j = 0; j < 6; ++j) {
      const int seg = w * 6 + j;  // 0..23 (W: 24 segs of 8 rows)
      const int n = seg * 8 + (lane >> 3);
      const short* g =
          &Wt[(size_t)n * C_ + k0 + (((lane & 7) ^ (n & 7)) << 3)];
      gl_lds16(g, (char*)&ws[buf][0] + seg * 1024);
    }
  };

  stage(0, 0);

#pragma unroll 1
  for (int it = 0; it < 16; ++it) {
    __syncthreads();
    const int cb = it & 1;
    if (it < 15) stage(cb ^ 1, (it + 1) * 64);
    const int arow = 16 * rg + l15;
    const int x7 = arow & 7;
    const float* xrow = &xs[cb][arow * 64];
    float4 fa = *reinterpret_cast<const float4*>(xrow + (((2 * lg) ^ x7) << 2));
    float4 fb = *reinterpret_cast<const float4*>(xrow + (((2 * lg + 1) ^ x7) << 2));
    float4 fc = *reinterpret_cast<const float4*>(xrow + (((2 * lg + 8) ^ x7) << 2));
    float4 fd = *reinterpret_cast<const float4*>(xrow + (((2 * lg + 9) ^ x7) << 2));
    short8 a0, a1;
    a0[0] = f2bf(fa.x); a0[1] = f2bf(fa.y); a0[2] = f2bf(fa.z); a0[3] = f2bf(fa.w);
    a0[4] = f2bf(fb.x); a0[5] = f2bf(fb.y); a0[6] = f2bf(fb.z); a0[7] = f2bf(fb.w);
    a1[0] = f2bf(fc.x); a1[1] = f2bf(fc.y); a1[2] = f2bf(fc.z); a1[3] = f2bf(fc.w);
    a1[4] = f2bf(fd.x); a1[5] = f2bf(fd.y); a1[6] = f2bf(fd.z); a1[7] = f2bf(fd.w);
#pragma unroll
    for (int nt = 0; nt < 6; ++nt) {
      const int n2 = 16 * (6 * ch + nt) + l15, n7 = n2 & 7;
      const short* wrow = &ws[cb][n2 * 64];
      short8 b0 = *reinterpret_cast<const short8*>(wrow + ((lg ^ n7) << 3));
      short8 b1 = *reinterpret_cast<const short8*>(wrow + (((4 + lg) ^ n7) << 3));
      acc[nt] = __builtin_amdgcn_mfma_f32_16x16x32_bf16(a0, b0, acc[nt], 0, 0, 0);
      acc[nt] = __builtin_amdgcn_mfma_f32_16x16x32_bf16(a1, b1, acc[nt], 0, 0, 0);
    }
  }

  // ---- epilogue ----
  const int strip = blockIdx.x * 2 + rg;
  const int rb = strip * 16;
#pragma unroll
  for (int nt = 0; nt < 6; ++nt) {
    const int ntg = 6 * ch + nt;  // global col-tile 0..11
    if (ntg < 8) {                // K (0-3) and Q (4-7) row-major stores
      short* O = (ntg < 4) ? Kp : Qp;
      const int col = (ntg & 3) * 16 + l15;
#pragma unroll
      for (int r = 0; r < 4; ++r)
        O[(size_t)(rb + lg * 4 + r) * H_ + col] = f2bf(acc[nt][r]);
    }
  }
  __syncthreads();  // xs dead; reuse for V transpose
  if (ch == 1) {    // waves 1,3 hold V tiles (ntg 8..11) for strips rg=0,1
    short* vl = reinterpret_cast<short*>(&xs[0][0]) + rg * (16 * 66);
#pragma unroll
    for (int nt = 2; nt < 6; ++nt)
#pragma unroll
      for (int r = 0; r < 4; ++r)
        vl[(lg * 4 + r) * 66 + (nt - 2) * 16 + l15] = f2bf(acc[nt][r]);
    asm volatile("s_waitcnt lgkmcnt(0)" ::: "memory");
    short8 o0, o1;
#pragma unroll
    for (int i = 0; i < 8; ++i) o0[i] = vl[i * 66 + lane];
#pragma unroll
    for (int i = 0; i < 8; ++i) o1[i] = vl[(8 + i) * 66 + lane];
    const int bb = strip >> 7, tb = (strip & 127) * 16;
    short* dst = &Vt[((size_t)bb * H_ + lane) * T_ + tb];
    *reinterpret_cast<short8*>(dst) = o0;
    *reinterpret_cast<short8*>(dst + 8) = o1;
  }
}

// ---------------------------------------------------------------------------
// attn: R15 structure + in-register P via k-slot permutation. MFMA contracts
// over slots; both PV operands use pi(lg,j) = 32kc + 16(j>>2) + 4lg + (j&3)
// (bijective per 32-key chunk). B (P^T) slot j = S[2kc+(j>>2)][j&3] — lane-
// local, zero LDS/cross-lane. A (V^T) reads two swizzled b64 chunks per frag
// (kv = 32kc+4lg and +16; slot ^= d&7, same staged layout). Ps buffer gone
// (LDS 64KB). Redundant odd-tail re-stage skipped (wave-uniform branch).
// ---------------------------------------------------------------------------
__global__ __launch_bounds__(256) void attn_kernel(
    const short* __restrict__ Kq, const short* __restrict__ Qk,
    const short* __restrict__ Vt, float* __restrict__ out) {
  __shared__ short Ks[4][64 * 64];  // [(per&1)*2 + tile][kv][h]
  __shared__ short Vs[4][64 * 64];  // [same][d][kv] (slot-swizzled source)
  const int t = threadIdx.x, w = t >> 6, lane = t & 63;
  const int l15 = lane & 15, lg = lane >> 4;
  const int batch = blockIdx.x & 7;
  const int g = blockIdx.x >> 3;                 // 0..63
  const int s = (g < 32) ? (63 - g) : (g - 32);  // balanced big/small pairing
  const int p = w & 1;                           // this wave's k-tile parity
  const int rg = w >> 1;                         // row group
  const short* Kb = Kq + (size_t)batch * T_ * H_;
  const short* Qb = Qk + (size_t)batch * T_ * H_;
  const short* Vb = Vt + (size_t)batch * H_ * T_;
  float* ob = out + (size_t)batch * T_ * H_;
  const f32x4 zf = {0.f, 0.f, 0.f, 0.f};
  const int k7 = l15 & 7;

  const int qbase = s * 32;
  const int qrow = qbase + rg * 16 + l15;
  const short8 qa0 = *reinterpret_cast<const short8*>(&Kb[(size_t)qrow * H_ + lg * 8]);
  const short8 qa1 = *reinterpret_cast<const short8*>(&Kb[(size_t)qrow * H_ + lg * 8 + 32]);
  const int nkt = (s >> 1) + 1;    // 64-key tiles
  const int np = (nkt + 1) >> 1;   // periods (2 tiles each)

  const int srow = lane >> 3;
  const int ssw = ((lane & 7) ^ srow) << 3;
  auto stage = [&](int per) {
    const int tj = 2 * per + (w >> 1);
    if (tj >= nkt) return;  // odd tail: skip (compute side guards kt < nkt)
    const int buf = (per & 1) * 2 + (w >> 1);
    const int kbase = tj * 64;
    const int h4 = (w & 1) * 4;
#pragma unroll
    for (int g2 = 0; g2 < 4; ++g2) {
      const int gg = h4 + g2;
      gl_lds16(&Qb[(size_t)(kbase + gg * 8 + srow) * H_ + ssw],
               (char*)&Ks[buf][0] + gg * 1024);
      gl_lds16(&Vb[(size_t)(gg * 8 + srow) * T_ + kbase + ssw],
               (char*)&Vs[buf][0] + gg * 1024);
    }
  };

  f32x4 O[4];
#pragma unroll
  for (int i = 0; i < 4; ++i) O[i] = zf;
  float m = -1e30f, l = 0.f;

  stage(0);

#pragma unroll 1
  for (int j = 0; j < np; ++j) {
    __syncthreads();  // drains staged loads + guards buffer reuse
    if (j + 1 < np) stage(j + 1);
    const int kt = 2 * j + p;
    if (kt < nkt) {
      const int cb = (j & 1) * 2 + p;
      const int kbase = kt * 64;
      f32x4 S[4];
      __builtin_amdgcn_s_setprio(1);
#pragma unroll
      for (int nt = 0; nt < 4; ++nt) {
        S[nt] = zf;
        const short* krow = &Ks[cb][(16 * nt + l15) * 64];
        short8 kf0 = *reinterpret_cast<const short8*>(&krow[(lg ^ k7) << 3]);
        short8 kf1 = *reinterpret_cast<const short8*>(&krow[((4 + lg) ^ k7) << 3]);
        S[nt] = __builtin_amdgcn_mfma_f32_16x16x32_bf16(kf0, qa0, S[nt], 0, 0, 0);
        S[nt] = __builtin_amdgcn_mfma_f32_16x16x32_bf16(kf1, qa1, S[nt], 0, 0, 0);
      }
      __builtin_amdgcn_s_setprio(0);
      if (kt == nkt - 1) {
#pragma unroll
        for (int nt = 0; nt < 4; ++nt) {
          const int klo = kbase + 16 * nt + 4 * lg;
#pragma unroll
          for (int r = 0; r < 4; ++r)
            if (klo + r > qrow) S[nt][r] = -1e30f;
        }
      }
      float mx0 = fmaxf(fmaxf(S[0][0], S[0][1]), fmaxf(S[0][2], S[0][3]));
      float mx1 = fmaxf(fmaxf(S[1][0], S[1][1]), fmaxf(S[1][2], S[1][3]));
      float mx2 = fmaxf(fmaxf(S[2][0], S[2][1]), fmaxf(S[2][2], S[2][3]));
      float mx3 = fmaxf(fmaxf(S[3][0], S[3][1]), fmaxf(S[3][2], S[3][3]));
      float mx = fmaxf(fmaxf(mx0, mx1), fmaxf(mx2, mx3));
      mx = fmaxf(mx, __shfl_xor(mx, 16));
      mx = fmaxf(mx, __shfl_xor(mx, 32));
      const float mn = fmaxf(m, mx);
      const float scv = exp2f(m - mn);
      m = mn;
      float rs = 0.f;
#pragma unroll
      for (int nt = 0; nt < 4; ++nt)
#pragma unroll
        for (int r = 0; r < 4; ++r) {
          const float pv = exp2f(S[nt][r] - mn);
          S[nt][r] = pv;
          rs += pv;
        }
      rs += __shfl_xor(rs, 16);
      rs += __shfl_xor(rs, 32);
      l = l * scv + rs;
#pragma unroll
      for (int nt = 0; nt < 4; ++nt) O[nt] *= scv;
      // PV with pi-permuted slots: pa is lane-local (no LDS round trip)
      const int d7 = l15 & 7;
      const int vo = 4 * (lg & 1);
      __builtin_amdgcn_s_setprio(1);
#pragma unroll
      for (int kc = 0; kc < 2; ++kc) {
        short8 pa;
#pragma unroll
        for (int jj = 0; jj < 8; ++jj)
          pa[jj] = f2bf(S[2 * kc + (jj >> 2)][jj & 3]);
        const int slo = ((4 * kc + (lg >> 1)) ^ d7) << 3;
        const int shi = ((4 * kc + 2 + (lg >> 1)) ^ d7) << 3;
#pragma unroll
        for (int nt = 0; nt < 4; ++nt) {
          const short* vrow = &Vs[cb][(16 * nt + l15) * 64];
          const bh4 vlo = *reinterpret_cast<const bh4*>(&vrow[slo + vo]);
          const bh4 vhi = *reinterpret_cast<const bh4*>(&vrow[shi + vo]);
          short8 vf;
          vf[0] = vlo[0]; vf[1] = vlo[1]; vf[2] = vlo[2]; vf[3] = vlo[3];
          vf[4] = vhi[0]; vf[5] = vhi[1]; vf[6] = vhi[2]; vf[7] = vhi[3];
          O[nt] = __builtin_amdgcn_mfma_f32_16x16x32_bf16(vf, pa, O[nt], 0, 0, 0);
        }
      }
      __builtin_amdgcn_s_setprio(0);
    }
  }

  // ---- 2-way parity combine (reuse dead stage LDS) ----
  __syncthreads();
  float* Po = reinterpret_cast<float*>(&Ks[0][0]);   // [4][16][68] f32 (17.4KB)
  float* Mlp = reinterpret_cast<float*>(&Vs[0][0]);  // [4][16][2]  f32
#pragma unroll
  for (int nt = 0; nt < 4; ++nt)
    *reinterpret_cast<f32x4*>(&Po[(w * 16 + l15) * 68 + 16 * nt + 4 * lg]) = O[nt];
  if (lane < 16) {
    Mlp[(w * 16 + l15) * 2 + 0] = m;
    Mlp[(w * 16 + l15) * 2 + 1] = l;
  }
  __syncthreads();
  {
    const int row = t >> 4, c4 = t & 15;
#pragma unroll
    for (int gg = 0; gg < 2; ++gg) {
      const int s0 = gg * 2, s1 = gg * 2 + 1;
      const float m0 = Mlp[(s0 * 16 + row) * 2], l0 = Mlp[(s0 * 16 + row) * 2 + 1];
      const float m1 = Mlp[(s1 * 16 + row) * 2], l1 = Mlp[(s1 * 16 + row) * 2 + 1];
      const float M = fmaxf(m0, m1);
      const float e0 = exp2f(m0 - M), e1 = exp2f(m1 - M);
      const float L = l0 * e0 + l1 * e1;
      const f32x4 o0 = *reinterpret_cast<const f32x4*>(&Po[(s0 * 16 + row) * 68 + c4 * 4]);
      const f32x4 o1 = *reinterpret_cast<const f32x4*>(&Po[(s1 * 16 + row) * 68 + c4 * 4]);
      const f32x4 res = (o0 * e0 + o1 * e1) * (1.f / L);
      *reinterpret_cast<f32x4*>(&ob[(size_t)(qbase + gg * 16 + row) * H_ + c4 * 4]) = res;
    }
  }
}

extern "C" void kernel_launch(void* const* d_in, const int* in_sizes, int n_in,
                              void* d_out, int out_size, void* d_ws, size_t ws_size,
                              hipStream_t stream) {
  const float* x = (const float*)d_in[0];
  const float* Wk = (const float*)d_in[1];
  const float* Wq = (const float*)d_in[2];
  const float* Wv = (const float*)d_in[3];
  float* out = (float*)d_out;

  short* Kp = (short*)d_ws;                  // [BT][64] bf16 (queries: x@Wk, scale*log2e folded)
  short* Qp = Kp + (size_t)BT_ * H_;         // [BT][64] bf16 (keys:    x@Wq)
  short* Vt = Qp + (size_t)BT_ * H_;         // [8][64][2048] bf16 (values^T)
  short* Wt = Vt + (size_t)BT_ * H_;         // [192][1024] bf16

  hipLaunchKernelGGL(prep_w, dim3(48), dim3(256), 0, stream, Wk, Wq, Wv, Wt);
  hipLaunchKernelGGL(proj_kernel, dim3(512), dim3(256), 0, stream, x, Wt, Kp, Qp, Vt);
  hipLaunchKernelGGL(attn_kernel, dim3(512), dim3(256), 0, stream, Kp, Qp, Vt, out);
}

// Round 18
// 54.228 us; speedup vs baseline: 1.1224x; 1.1066x over previous
//
#include <hip/hip_runtime.h>
#include <cstdint>

#define B_ 8
#define T_ 2048
#define C_ 1024
#define H_ 64
#define BT_ (B_ * T_)

typedef short short8 __attribute__((ext_vector_type(8)));
typedef short bh4 __attribute__((ext_vector_type(4)));
typedef float f32x4 __attribute__((ext_vector_type(4)));

__device__ inline short f2bf(float f) {
  uint32_t u = __float_as_uint(f);
  u += 0x7fffu + ((u >> 16) & 1u);  // RNE; inputs finite
  return (short)(u >> 16);
}

// async global->LDS, 16B per lane; LDS dest = uniform base + lane*16 (HW rule)
__device__ __forceinline__ void gl_lds16(const void* g, void* l) {
  __builtin_amdgcn_global_load_lds(
      (const __attribute__((address_space(1))) unsigned int*)g,
      (__attribute__((address_space(3))) unsigned int*)l, 16, 0, 0);
}

// ---------------------------------------------------------------------------
// prep_w: Wk/Wq/Wv [1024][64] fp32 -> Wt [192][1024] bf16 (transposed).
// Folded into Wk: score scale 1024^-0.5 AND log2(e) (softmax in log2 domain).
// ---------------------------------------------------------------------------
__global__ __launch_bounds__(256) void prep_w(
    const float* __restrict__ Wk, const float* __restrict__ Wq,
    const float* __restrict__ Wv, short* __restrict__ Wt) {
  __shared__ float wl[64][68];
  const int mat = blockIdx.x >> 4;
  const int kc = blockIdx.x & 15;
  const float* W = (mat == 0) ? Wk : (mat == 1) ? Wq : Wv;
  const float sc = (mat == 0) ? 0.03125f * 1.44269504088896f : 1.0f;
  const int t = threadIdx.x;
  const int k0 = kc * 64;
#pragma unroll
  for (int j = 0; j < 4; ++j) {
    int s = t + 256 * j;
    int kr = s >> 4, cf = s & 15;
    float4 v = *reinterpret_cast<const float4*>(&W[(size_t)(k0 + kr) * H_ + cf * 4]);
    wl[kr][cf * 4 + 0] = v.x; wl[kr][cf * 4 + 1] = v.y;
    wl[kr][cf * 4 + 2] = v.z; wl[kr][cf * 4 + 3] = v.w;
  }
  __syncthreads();
#pragma unroll
  for (int j = 0; j < 2; ++j) {
    int s = t + 256 * j;
    int n = s >> 3, g = s & 7;
    short8 o;
#pragma unroll
    for (int i = 0; i < 8; ++i) o[i] = f2bf(wl[8 * g + i][n] * sc);
    *reinterpret_cast<short8*>(&Wt[(size_t)(mat * 64 + n) * C_ + k0 + 8 * g]) = o;
  }
}

// ---------------------------------------------------------------------------
// proj: R15 version verbatim (measured best). 512 blocks x 256 thr.
// ---------------------------------------------------------------------------
__global__ __launch_bounds__(256, 1) void proj_kernel(
    const float* __restrict__ x, const short* __restrict__ Wt,
    short* __restrict__ Kp, short* __restrict__ Qp, short* __restrict__ Vt) {
  __shared__ float xs[2][32 * 64];   // 8KB each
  __shared__ short ws[2][192 * 64];  // 24KB each
  const int t = threadIdx.x;
  const int w = t >> 6, lane = t & 63;
  const int l15 = lane & 15, lg = lane >> 4;
  const int rg = w >> 1, ch = w & 1;
  const int rowBase = blockIdx.x * 32;

  f32x4 acc[6];
  const f32x4 zf = {0.f, 0.f, 0.f, 0.f};
#pragma unroll
  for (int i = 0; i < 6; ++i) acc[i] = zf;

  auto stage = [&](int buf, int k0) {
#pragma unroll
    for (int j = 0; j < 2; ++j) {
      const int seg = w * 2 + j;
      const int r = seg * 4 + (lane >> 4);
      const float* g =
          &x[(size_t)(rowBase + r) * C_ + k0 + (((lane & 15) ^ (r & 7)) << 2)];
      gl_lds16(g, (char*)&xs[buf][0] + seg * 1024);
    }
#pragma unroll
    for (int j = 0; j < 6; ++j) {
      const int seg = w * 6 + j;
      const int n = seg * 8 + (lane >> 3);
      const short* g =
          &Wt[(size_t)n * C_ + k0 + (((lane & 7) ^ (n & 7)) << 3)];
      gl_lds16(g, (char*)&ws[buf][0] + seg * 1024);
    }
  };

  stage(0, 0);

#pragma unroll 1
  for (int it = 0; it < 16; ++it) {
    __syncthreads();
    const int cb = it & 1;
    if (it < 15) stage(cb ^ 1, (it + 1) * 64);
    const int arow = 16 * rg + l15;
    const int x7 = arow & 7;
    const float* xrow = &xs[cb][arow * 64];
    float4 fa = *reinterpret_cast<const float4*>(xrow + (((2 * lg) ^ x7) << 2));
    float4 fb = *reinterpret_cast<const float4*>(xrow + (((2 * lg + 1) ^ x7) << 2));
    float4 fc = *reinterpret_cast<const float4*>(xrow + (((2 * lg + 8) ^ x7) << 2));
    float4 fd = *reinterpret_cast<const float4*>(xrow + (((2 * lg + 9) ^ x7) << 2));
    short8 a0, a1;
    a0[0] = f2bf(fa.x); a0[1] = f2bf(fa.y); a0[2] = f2bf(fa.z); a0[3] = f2bf(fa.w);
    a0[4] = f2bf(fb.x); a0[5] = f2bf(fb.y); a0[6] = f2bf(fb.z); a0[7] = f2bf(fb.w);
    a1[0] = f2bf(fc.x); a1[1] = f2bf(fc.y); a1[2] = f2bf(fc.z); a1[3] = f2bf(fc.w);
    a1[4] = f2bf(fd.x); a1[5] = f2bf(fd.y); a1[6] = f2bf(fd.z); a1[7] = f2bf(fd.w);
#pragma unroll
    for (int nt = 0; nt < 6; ++nt) {
      const int n2 = 16 * (6 * ch + nt) + l15, n7 = n2 & 7;
      const short* wrow = &ws[cb][n2 * 64];
      short8 b0 = *reinterpret_cast<const short8*>(wrow + ((lg ^ n7) << 3));
      short8 b1 = *reinterpret_cast<const short8*>(wrow + (((4 + lg) ^ n7) << 3));
      acc[nt] = __builtin_amdgcn_mfma_f32_16x16x32_bf16(a0, b0, acc[nt], 0, 0, 0);
      acc[nt] = __builtin_amdgcn_mfma_f32_16x16x32_bf16(a1, b1, acc[nt], 0, 0, 0);
    }
  }

  const int strip = blockIdx.x * 2 + rg;
  const int rb = strip * 16;
#pragma unroll
  for (int nt = 0; nt < 6; ++nt) {
    const int ntg = 6 * ch + nt;
    if (ntg < 8) {
      short* O = (ntg < 4) ? Kp : Qp;
      const int col = (ntg & 3) * 16 + l15;
#pragma unroll
      for (int r = 0; r < 4; ++r)
        O[(size_t)(rb + lg * 4 + r) * H_ + col] = f2bf(acc[nt][r]);
    }
  }
  __syncthreads();
  if (ch == 1) {
    short* vl = reinterpret_cast<short*>(&xs[0][0]) + rg * (16 * 66);
#pragma unroll
    for (int nt = 2; nt < 6; ++nt)
#pragma unroll
      for (int r = 0; r < 4; ++r)
        vl[(lg * 4 + r) * 66 + (nt - 2) * 16 + l15] = f2bf(acc[nt][r]);
    asm volatile("s_waitcnt lgkmcnt(0)" ::: "memory");
    short8 o0, o1;
#pragma unroll
    for (int i = 0; i < 8; ++i) o0[i] = vl[i * 66 + lane];
#pragma unroll
    for (int i = 0; i < 8; ++i) o1[i] = vl[(8 + i) * 66 + lane];
    const int bb = strip >> 7, tb = (strip & 127) * 16;
    short* dst = &Vt[((size_t)bb * H_ + lane) * T_ + tb];
    *reinterpret_cast<short8*>(dst) = o0;
    *reinterpret_cast<short8*>(dst + 8) = o1;
  }
}

// ---------------------------------------------------------------------------
// attn: 512 blocks x 512 thr (8 waves = 4 row-groups x 2 k-parities).
// Block = (batch, 64-row q-strip sidx, k-half h): half h owns global tiles
// = h mod 2; wave (rg,p) computes tiles 4i+2p+h for rows rg*16..+15. Each
// staged 64-key tile (16KB K+V) serves 64 q-rows -> block-periods halve vs
// R15 (4224 -> 2112) and staged L2 bytes halve. LDS 64KB -> 2 blocks/CU =
// 16 waves/CU; CU-slot pairing (q<32: s=31-q,h=0 else s=q-32,h=1) balances
// paired period counts. PV uses R17's pi-permuted in-register P. Partials
// (unnormalized O, m, l; log2 domain) -> Pg/Mg; combine_kernel merges halves.
// ---------------------------------------------------------------------------
__global__ __launch_bounds__(512) void attn_kernel(
    const short* __restrict__ Kq, const short* __restrict__ Qk,
    const short* __restrict__ Vt, float* __restrict__ Pg,
    float* __restrict__ Mg) {
  __shared__ short Ks[4][64 * 64];  // [(per&1)*2 + tile-in-period][kv][h]
  __shared__ short Vs[4][64 * 64];  // [same][d][kv]
  const int t = threadIdx.x, w = t >> 6, lane = t & 63;
  const int l15 = lane & 15, lg = lane >> 4;
  const int batch = blockIdx.x & 7;
  const int q = blockIdx.x >> 3;                    // 0..63
  const int sidx = (q < 32) ? (31 - q) : (q - 32);  // 64-row strip
  const int h = (q < 32) ? 0 : 1;                   // k-half
  const int p = w & 1, rg = w >> 1;                 // compute roles
  const short* Kb = Kq + (size_t)batch * T_ * H_;
  const short* Qb = Qk + (size_t)batch * T_ * H_;
  const short* Vb = Vt + (size_t)batch * H_ * T_;
  const f32x4 zf = {0.f, 0.f, 0.f, 0.f};
  const int k7 = l15 & 7;

  const int qbase = sidx * 64;
  const int qrow = qbase + rg * 16 + l15;
  const short8 qa0 = *reinterpret_cast<const short8*>(&Kb[(size_t)qrow * H_ + lg * 8]);
  const short8 qa1 = *reinterpret_cast<const short8*>(&Kb[(size_t)qrow * H_ + lg * 8 + 32]);
  const int ntiles = sidx + 1;  // global 64-key tiles 0..sidx
  const int nlist = (h == 0) ? ((ntiles + 1) >> 1) : (ntiles >> 1);
  const int np = (nlist + 1) >> 1;  // periods (2 list entries each)

  // staging roles: tp = w>>2 (tile in period), kind = (w>>1)&1 (K/V), q2 = w&1
  const int tp = w >> 2, kind = (w >> 1) & 1, q2 = w & 1;
  const int srow = lane >> 3;
  const int ssw = ((lane & 7) ^ srow) << 3;
  auto stage = [&](int per) {
    const int le = 2 * per + tp;
    if (le >= nlist) return;
    const int gkt = 2 * le + h;
    const int buf = (per & 1) * 2 + tp;
    const int kbase = gkt * 64;
    if (kind == 0) {
#pragma unroll
      for (int g2 = 0; g2 < 4; ++g2) {
        const int gg = q2 * 4 + g2;
        gl_lds16(&Qb[(size_t)(kbase + gg * 8 + srow) * H_ + ssw],
                 (char*)&Ks[buf][0] + gg * 1024);
      }
    } else {
#pragma unroll
      for (int g2 = 0; g2 < 4; ++g2) {
        const int gg = q2 * 4 + g2;
        gl_lds16(&Vb[(size_t)(gg * 8 + srow) * T_ + kbase + ssw],
                 (char*)&Vs[buf][0] + gg * 1024);
      }
    }
  };

  f32x4 O[4];
#pragma unroll
  for (int i = 0; i < 4; ++i) O[i] = zf;
  float m = -1e30f, l = 0.f;

  stage(0);

#pragma unroll 1
  for (int i = 0; i < np; ++i) {
    __syncthreads();  // drains staged loads + guards buffer reuse
    if (i + 1 < np) stage(i + 1);
    const int le = 2 * i + p;
    if (le < nlist) {
      const int gkt = 2 * le + h;
      const int cb = (i & 1) * 2 + p;
      const int kbase = gkt * 64;
      f32x4 S[4];
      __builtin_amdgcn_s_setprio(1);
#pragma unroll
      for (int nt = 0; nt < 4; ++nt) {
        S[nt] = zf;
        const short* krow = &Ks[cb][(16 * nt + l15) * 64];
        short8 kf0 = *reinterpret_cast<const short8*>(&krow[(lg ^ k7) << 3]);
        short8 kf1 = *reinterpret_cast<const short8*>(&krow[((4 + lg) ^ k7) << 3]);
        S[nt] = __builtin_amdgcn_mfma_f32_16x16x32_bf16(kf0, qa0, S[nt], 0, 0, 0);
        S[nt] = __builtin_amdgcn_mfma_f32_16x16x32_bf16(kf1, qa1, S[nt], 0, 0, 0);
      }
      __builtin_amdgcn_s_setprio(0);
      if (gkt == sidx) {  // only the strip's last global tile crosses diagonal
#pragma unroll
        for (int nt = 0; nt < 4; ++nt) {
          const int klo = kbase + 16 * nt + 4 * lg;
#pragma unroll
          for (int r = 0; r < 4; ++r)
            if (klo + r > qrow) S[nt][r] = -1e30f;
        }
      }
      float mx0 = fmaxf(fmaxf(S[0][0], S[0][1]), fmaxf(S[0][2], S[0][3]));
      float mx1 = fmaxf(fmaxf(S[1][0], S[1][1]), fmaxf(S[1][2], S[1][3]));
      float mx2 = fmaxf(fmaxf(S[2][0], S[2][1]), fmaxf(S[2][2], S[2][3]));
      float mx3 = fmaxf(fmaxf(S[3][0], S[3][1]), fmaxf(S[3][2], S[3][3]));
      float mx = fmaxf(fmaxf(mx0, mx1), fmaxf(mx2, mx3));
      mx = fmaxf(mx, __shfl_xor(mx, 16));
      mx = fmaxf(mx, __shfl_xor(mx, 32));
      const float mn = fmaxf(m, mx);
      const float scv = exp2f(m - mn);
      m = mn;
      float rs = 0.f;
#pragma unroll
      for (int nt = 0; nt < 4; ++nt)
#pragma unroll
        for (int r = 0; r < 4; ++r) {
          const float pv = exp2f(S[nt][r] - mn);
          S[nt][r] = pv;
          rs += pv;
        }
      rs += __shfl_xor(rs, 16);
      rs += __shfl_xor(rs, 32);
      l = l * scv + rs;
#pragma unroll
      for (int nt = 0; nt < 4; ++nt) O[nt] *= scv;
      // PV with pi-permuted slots: pa lane-local (R17, refcheck'd)
      const int d7 = l15 & 7;
      const int vo = 4 * (lg & 1);
      __builtin_amdgcn_s_setprio(1);
#pragma unroll
      for (int kc = 0; kc < 2; ++kc) {
        short8 pa;
#pragma unroll
        for (int jj = 0; jj < 8; ++jj)
          pa[jj] = f2bf(S[2 * kc + (jj >> 2)][jj & 3]);
        const int slo = ((4 * kc + (lg >> 1)) ^ d7) << 3;
        const int shi = ((4 * kc + 2 + (lg >> 1)) ^ d7) << 3;
#pragma unroll
        for (int nt = 0; nt < 4; ++nt) {
          const short* vrow = &Vs[cb][(16 * nt + l15) * 64];
          const bh4 vlo = *reinterpret_cast<const bh4*>(&vrow[slo + vo]);
          const bh4 vhi = *reinterpret_cast<const bh4*>(&vrow[shi + vo]);
          short8 vf;
          vf[0] = vlo[0]; vf[1] = vlo[1]; vf[2] = vlo[2]; vf[3] = vlo[3];
          vf[4] = vhi[0]; vf[5] = vhi[1]; vf[6] = vhi[2]; vf[7] = vhi[3];
          O[nt] = __builtin_amdgcn_mfma_f32_16x16x32_bf16(vf, pa, O[nt], 0, 0, 0);
        }
      }
      __builtin_amdgcn_s_setprio(0);
    }
  }

  // ---- in-block 2-way parity merge (dead stage LDS), publish half-partial --
  __syncthreads();
  float* Po = reinterpret_cast<float*>(&Ks[0][0]);   // [8][16][64] f32 = 32KB
  float* Mlp = reinterpret_cast<float*>(&Vs[0][0]);  // [8][16][2]  f32
#pragma unroll
  for (int nt = 0; nt < 4; ++nt)
    *reinterpret_cast<f32x4*>(&Po[(w * 16 + l15) * 64 + 16 * nt + 4 * lg]) = O[nt];
  if (lane < 16) {
    Mlp[(w * 16 + l15) * 2 + 0] = m;
    Mlp[(w * 16 + l15) * 2 + 1] = l;
  }
  __syncthreads();
  {
    const int c4 = t & 15;
#pragma unroll
    for (int hh = 0; hh < 2; ++hh) {
      const int lr = (t >> 4) + 32 * hh;  // 0..63 (local row)
      const int w0 = (lr >> 4) * 2, w1 = w0 + 1;
      const int r = lr & 15;
      const float m0 = Mlp[(w0 * 16 + r) * 2], l0 = Mlp[(w0 * 16 + r) * 2 + 1];
      const float m1 = Mlp[(w1 * 16 + r) * 2], l1 = Mlp[(w1 * 16 + r) * 2 + 1];
      const float M = fmaxf(m0, m1);
      const float e0 = exp2f(m0 - M), e1 = exp2f(m1 - M);
      const float L = l0 * e0 + l1 * e1;
      const f32x4 o0 = *reinterpret_cast<const f32x4*>(&Po[(w0 * 16 + r) * 64 + c4 * 4]);
      const f32x4 o1 = *reinterpret_cast<const f32x4*>(&Po[(w1 * 16 + r) * 64 + c4 * 4]);
      const f32x4 om = o0 * e0 + o1 * e1;  // unnormalized
      const size_t gr = (size_t)batch * T_ + qbase + lr;
      *reinterpret_cast<f32x4*>(&Pg[((size_t)h * BT_ + gr) * H_ + c4 * 4]) = om;
      if (c4 == 0) {
        Mg[((size_t)h * BT_ + gr) * 2 + 0] = M;
        Mg[((size_t)h * BT_ + gr) * 2 + 1] = L;
      }
    }
  }
}

// ---------------------------------------------------------------------------
// combine: merge the two k-half partials per row. 512 blocks x 256 thr,
// 2 f4-tasks/thread. exp2 algebra absorbs empty halves (m=-1e30, l=0).
// ---------------------------------------------------------------------------
__global__ __launch_bounds__(256) void combine_kernel(
    const float* __restrict__ Pg, const float* __restrict__ Mg,
    float* __restrict__ out) {
  const int t = threadIdx.x;
#pragma unroll
  for (int k = 0; k < 2; ++k) {
    const int task = blockIdx.x * 512 + k * 256 + t;
    const int row = task >> 4;  // 0..16383
    const int c4 = task & 15;
    const float M0 = Mg[(size_t)row * 2], L0 = Mg[(size_t)row * 2 + 1];
    const float M1 = Mg[((size_t)BT_ + row) * 2], L1 = Mg[((size_t)BT_ + row) * 2 + 1];
    const float M = fmaxf(M0, M1);
    const float e0 = exp2f(M0 - M), e1 = exp2f(M1 - M);
    const float L = L0 * e0 + L1 * e1;
    const f32x4 o0 = *reinterpret_cast<const f32x4*>(&Pg[(size_t)row * H_ + c4 * 4]);
    const f32x4 o1 = *reinterpret_cast<const f32x4*>(&Pg[((size_t)BT_ + row) * H_ + c4 * 4]);
    const f32x4 res = (o0 * e0 + o1 * e1) * (1.f / L);
    *reinterpret_cast<f32x4*>(&out[(size_t)row * H_ + c4 * 4]) = res;
  }
}

extern "C" void kernel_launch(void* const* d_in, const int* in_sizes, int n_in,
                              void* d_out, int out_size, void* d_ws, size_t ws_size,
                              hipStream_t stream) {
  const float* x = (const float*)d_in[0];
  const float* Wk = (const float*)d_in[1];
  const float* Wq = (const float*)d_in[2];
  const float* Wv = (const float*)d_in[3];
  float* out = (float*)d_out;

  short* Kp = (short*)d_ws;                  // [BT][64] bf16 (queries: x@Wk, scale*log2e folded)
  short* Qp = Kp + (size_t)BT_ * H_;         // [BT][64] bf16 (keys:    x@Wq)
  short* Vt = Qp + (size_t)BT_ * H_;         // [8][64][2048] bf16 (values^T)
  short* Wt = Vt + (size_t)BT_ * H_;         // [192][1024] bf16
  float* Pg = (float*)(Wt + 192 * C_);       // [2][BT][64] f32 partials (8MB)
  float* Mg = Pg + (size_t)2 * BT_ * H_;     // [2][BT][2]  f32 (m,l)

  hipLaunchKernelGGL(prep_w, dim3(48), dim3(256), 0, stream, Wk, Wq, Wv, Wt);
  hipLaunchKernelGGL(proj_kernel, dim3(512), dim3(256), 0, stream, x, Wt, Kp, Qp, Vt);
  hipLaunchKernelGGL(attn_kernel, dim3(512), dim3(512), 0, stream, Kp, Qp, Vt, Pg, Mg);
  hipLaunchKernelGGL(combine_kernel, dim3(512), dim3(256), 0, stream, Pg, Mg, out);
}

// Round 19
// 52.558 us; speedup vs baseline: 1.1581x; 1.0318x over previous
//
#include <hip/hip_runtime.h>
#include <cstdint>

#define B_ 8
#define T_ 2048
#define C_ 1024
#define H_ 64
#define BT_ (B_ * T_)

typedef short short8 __attribute__((ext_vector_type(8)));
typedef short bh4 __attribute__((ext_vector_type(4)));
typedef float f32x4 __attribute__((ext_vector_type(4)));

__device__ inline short f2bf(float f) {
  uint32_t u = __float_as_uint(f);
  u += 0x7fffu + ((u >> 16) & 1u);  // RNE; inputs finite
  return (short)(u >> 16);
}

// async global->LDS, 16B per lane; LDS dest = uniform base + lane*16 (HW rule)
__device__ __forceinline__ void gl_lds16(const void* g, void* l) {
  __builtin_amdgcn_global_load_lds(
      (const __attribute__((address_space(1))) unsigned int*)g,
      (__attribute__((address_space(3))) unsigned int*)l, 16, 0, 0);
}

// ---------------------------------------------------------------------------
// prep_w: Wk/Wq/Wv [1024][64] fp32 -> Wt [192][1024] bf16 (transposed).
// Folded into Wk: score scale 1024^-0.5 AND log2(e) (softmax in log2 domain).
// ---------------------------------------------------------------------------
__global__ __launch_bounds__(256) void prep_w(
    const float* __restrict__ Wk, const float* __restrict__ Wq,
    const float* __restrict__ Wv, short* __restrict__ Wt) {
  __shared__ float wl[64][68];
  const int mat = blockIdx.x >> 4;
  const int kc = blockIdx.x & 15;
  const float* W = (mat == 0) ? Wk : (mat == 1) ? Wq : Wv;
  const float sc = (mat == 0) ? 0.03125f * 1.44269504088896f : 1.0f;
  const int t = threadIdx.x;
  const int k0 = kc * 64;
#pragma unroll
  for (int j = 0; j < 4; ++j) {
    int s = t + 256 * j;
    int kr = s >> 4, cf = s & 15;
    float4 v = *reinterpret_cast<const float4*>(&W[(size_t)(k0 + kr) * H_ + cf * 4]);
    wl[kr][cf * 4 + 0] = v.x; wl[kr][cf * 4 + 1] = v.y;
    wl[kr][cf * 4 + 2] = v.z; wl[kr][cf * 4 + 3] = v.w;
  }
  __syncthreads();
#pragma unroll
  for (int j = 0; j < 2; ++j) {
    int s = t + 256 * j;
    int n = s >> 3, g = s & 7;
    short8 o;
#pragma unroll
    for (int i = 0; i < 8; ++i) o[i] = f2bf(wl[8 * g + i][n] * sc);
    *reinterpret_cast<short8*>(&Wt[(size_t)(mat * 64 + n) * C_ + k0 + 8 * g]) = o;
  }
}

// ---------------------------------------------------------------------------
// proj: R15 version verbatim (measured best). 512 blocks x 256 thr.
// ---------------------------------------------------------------------------
__global__ __launch_bounds__(256, 1) void proj_kernel(
    const float* __restrict__ x, const short* __restrict__ Wt,
    short* __restrict__ Kp, short* __restrict__ Qp, short* __restrict__ Vt) {
  __shared__ float xs[2][32 * 64];   // 8KB each
  __shared__ short ws[2][192 * 64];  // 24KB each
  const int t = threadIdx.x;
  const int w = t >> 6, lane = t & 63;
  const int l15 = lane & 15, lg = lane >> 4;
  const int rg = w >> 1, ch = w & 1;
  const int rowBase = blockIdx.x * 32;

  f32x4 acc[6];
  const f32x4 zf = {0.f, 0.f, 0.f, 0.f};
#pragma unroll
  for (int i = 0; i < 6; ++i) acc[i] = zf;

  auto stage = [&](int buf, int k0) {
#pragma unroll
    for (int j = 0; j < 2; ++j) {
      const int seg = w * 2 + j;
      const int r = seg * 4 + (lane >> 4);
      const float* g =
          &x[(size_t)(rowBase + r) * C_ + k0 + (((lane & 15) ^ (r & 7)) << 2)];
      gl_lds16(g, (char*)&xs[buf][0] + seg * 1024);
    }
#pragma unroll
    for (int j = 0; j < 6; ++j) {
      const int seg = w * 6 + j;
      const int n = seg * 8 + (lane >> 3);
      const short* g =
          &Wt[(size_t)n * C_ + k0 + (((lane & 7) ^ (n & 7)) << 3)];
      gl_lds16(g, (char*)&ws[buf][0] + seg * 1024);
    }
  };

  stage(0, 0);

#pragma unroll 1
  for (int it = 0; it < 16; ++it) {
    __syncthreads();
    const int cb = it & 1;
    if (it < 15) stage(cb ^ 1, (it + 1) * 64);
    const int arow = 16 * rg + l15;
    const int x7 = arow & 7;
    const float* xrow = &xs[cb][arow * 64];
    float4 fa = *reinterpret_cast<const float4*>(xrow + (((2 * lg) ^ x7) << 2));
    float4 fb = *reinterpret_cast<const float4*>(xrow + (((2 * lg + 1) ^ x7) << 2));
    float4 fc = *reinterpret_cast<const float4*>(xrow + (((2 * lg + 8) ^ x7) << 2));
    float4 fd = *reinterpret_cast<const float4*>(xrow + (((2 * lg + 9) ^ x7) << 2));
    short8 a0, a1;
    a0[0] = f2bf(fa.x); a0[1] = f2bf(fa.y); a0[2] = f2bf(fa.z); a0[3] = f2bf(fa.w);
    a0[4] = f2bf(fb.x); a0[5] = f2bf(fb.y); a0[6] = f2bf(fb.z); a0[7] = f2bf(fb.w);
    a1[0] = f2bf(fc.x); a1[1] = f2bf(fc.y); a1[2] = f2bf(fc.z); a1[3] = f2bf(fc.w);
    a1[4] = f2bf(fd.x); a1[5] = f2bf(fd.y); a1[6] = f2bf(fd.z); a1[7] = f2bf(fd.w);
#pragma unroll
    for (int nt = 0; nt < 6; ++nt) {
      const int n2 = 16 * (6 * ch + nt) + l15, n7 = n2 & 7;
      const short* wrow = &ws[cb][n2 * 64];
      short8 b0 = *reinterpret_cast<const short8*>(wrow + ((lg ^ n7) << 3));
      short8 b1 = *reinterpret_cast<const short8*>(wrow + (((4 + lg) ^ n7) << 3));
      acc[nt] = __builtin_amdgcn_mfma_f32_16x16x32_bf16(a0, b0, acc[nt], 0, 0, 0);
      acc[nt] = __builtin_amdgcn_mfma_f32_16x16x32_bf16(a1, b1, acc[nt], 0, 0, 0);
    }
  }

  const int strip = blockIdx.x * 2 + rg;
  const int rb = strip * 16;
#pragma unroll
  for (int nt = 0; nt < 6; ++nt) {
    const int ntg = 6 * ch + nt;
    if (ntg < 8) {
      short* O = (ntg < 4) ? Kp : Qp;
      const int col = (ntg & 3) * 16 + l15;
#pragma unroll
      for (int r = 0; r < 4; ++r)
        O[(size_t)(rb + lg * 4 + r) * H_ + col] = f2bf(acc[nt][r]);
    }
  }
  __syncthreads();
  if (ch == 1) {
    short* vl = reinterpret_cast<short*>(&xs[0][0]) + rg * (16 * 66);
#pragma unroll
    for (int nt = 2; nt < 6; ++nt)
#pragma unroll
      for (int r = 0; r < 4; ++r)
        vl[(lg * 4 + r) * 66 + (nt - 2) * 16 + l15] = f2bf(acc[nt][r]);
    asm volatile("s_waitcnt lgkmcnt(0)" ::: "memory");
    short8 o0, o1;
#pragma unroll
    for (int i = 0; i < 8; ++i) o0[i] = vl[i * 66 + lane];
#pragma unroll
    for (int i = 0; i < 8; ++i) o1[i] = vl[(8 + i) * 66 + lane];
    const int bb = strip >> 7, tb = (strip & 127) * 16;
    short* dst = &Vt[((size_t)bb * H_ + lane) * T_ + tb];
    *reinterpret_cast<short8*>(dst) = o0;
    *reinterpret_cast<short8*>(dst + 8) = o1;
  }
}

// ---------------------------------------------------------------------------
// attn: 512 blocks x 512 thr (8 waves = 8 row-groups of 16 rows).
// Block = (batch, 128-row q-strip sidx, k-quarter qh): owns global tiles
// = qh (mod 4). Each staged 64-key tile serves 128 q-rows; each wave
// computes BOTH tiles of a period sequentially -> periods/CU halve again
// vs R18 (8.25 -> 4.25) and staged L2 bytes halve (~34MB). Waves own
// disjoint rows -> no in-block merge (partials written directly). Pairing
// g=rest>>2, s = g<8 ? 15-g : g-8 balances CU-slot period sums. Mask guard:
// tiles gkt >= 2*sidx cross the diagonal. PV uses pi-permuted in-register P.
// Partials (unnormalized O, m, l; log2) -> Pg/Mg; combine merges 4 quarters.
// ---------------------------------------------------------------------------
__global__ __launch_bounds__(512) void attn_kernel(
    const short* __restrict__ Kq, const short* __restrict__ Qk,
    const short* __restrict__ Vt, float* __restrict__ Pg,
    float* __restrict__ Mg) {
  __shared__ short Ks[4][64 * 64];  // [(per&1)*2 + tile-in-period][kv][h]
  __shared__ short Vs[4][64 * 64];  // [same][d][kv]
  const int t = threadIdx.x, w = t >> 6, lane = t & 63;
  const int l15 = lane & 15, lg = lane >> 4;
  const int batch = blockIdx.x & 7;
  const int rest = blockIdx.x >> 3;  // 0..63
  const int qh = rest & 3;           // k-quarter
  const int g = rest >> 2;           // 0..15
  const int sidx = (g < 8) ? (15 - g) : (g - 8);  // balanced pairing
  const int rg = w;                  // row group (16 rows each)
  const short* Kb = Kq + (size_t)batch * T_ * H_;
  const short* Qb = Qk + (size_t)batch * T_ * H_;
  const short* Vb = Vt + (size_t)batch * H_ * T_;
  const f32x4 zf = {0.f, 0.f, 0.f, 0.f};
  const int k7 = l15 & 7;

  const int qbase = sidx * 128;
  const int qrow = qbase + rg * 16 + l15;
  const short8 qa0 = *reinterpret_cast<const short8*>(&Kb[(size_t)qrow * H_ + lg * 8]);
  const short8 qa1 = *reinterpret_cast<const short8*>(&Kb[(size_t)qrow * H_ + lg * 8 + 32]);
  const int ntop = 2 * sidx + 1;  // last global tile index for this strip
  const int nlist = (ntop >= qh) ? (((ntop - qh) >> 2) + 1) : 0;
  const int np = (nlist + 1) >> 1;  // periods (2 list entries each)

  // staging roles: tp = w>>2 (tile in period), kind = (w>>1)&1 (K/V), q2 = w&1
  const int tp = w >> 2, kind = (w >> 1) & 1, q2 = w & 1;
  const int srow = lane >> 3;
  const int ssw = ((lane & 7) ^ srow) << 3;
  auto stage = [&](int per) {
    const int le = 2 * per + tp;
    if (le >= nlist) return;
    const int gkt = 4 * le + qh;
    const int buf = (per & 1) * 2 + tp;
    const int kbase = gkt * 64;
    if (kind == 0) {
#pragma unroll
      for (int g2 = 0; g2 < 4; ++g2) {
        const int gg = q2 * 4 + g2;
        gl_lds16(&Qb[(size_t)(kbase + gg * 8 + srow) * H_ + ssw],
                 (char*)&Ks[buf][0] + gg * 1024);
      }
    } else {
#pragma unroll
      for (int g2 = 0; g2 < 4; ++g2) {
        const int gg = q2 * 4 + g2;
        gl_lds16(&Vb[(size_t)(gg * 8 + srow) * T_ + kbase + ssw],
                 (char*)&Vs[buf][0] + gg * 1024);
      }
    }
  };

  f32x4 O[4];
#pragma unroll
  for (int i = 0; i < 4; ++i) O[i] = zf;
  float m = -1e30f, l = 0.f;

  stage(0);

#pragma unroll 1
  for (int i = 0; i < np; ++i) {
    __syncthreads();  // drains staged loads + guards buffer reuse
    if (i + 1 < np) stage(i + 1);
#pragma unroll 1
    for (int tt = 0; tt < 2; ++tt) {
      const int le = 2 * i + tt;
      if (le < nlist) {
        const int gkt = 4 * le + qh;
        const int cb = (i & 1) * 2 + tt;
        const int kbase = gkt * 64;
        f32x4 S[4];
        __builtin_amdgcn_s_setprio(1);
#pragma unroll
        for (int nt = 0; nt < 4; ++nt) {
          S[nt] = zf;
          const short* krow = &Ks[cb][(16 * nt + l15) * 64];
          short8 kf0 = *reinterpret_cast<const short8*>(&krow[(lg ^ k7) << 3]);
          short8 kf1 = *reinterpret_cast<const short8*>(&krow[((4 + lg) ^ k7) << 3]);
          S[nt] = __builtin_amdgcn_mfma_f32_16x16x32_bf16(kf0, qa0, S[nt], 0, 0, 0);
          S[nt] = __builtin_amdgcn_mfma_f32_16x16x32_bf16(kf1, qa1, S[nt], 0, 0, 0);
        }
        __builtin_amdgcn_s_setprio(0);
        if (gkt >= 2 * sidx) {  // diagonal-crossing tiles (2 per strip)
#pragma unroll
          for (int nt = 0; nt < 4; ++nt) {
            const int klo = kbase + 16 * nt + 4 * lg;
#pragma unroll
            for (int r = 0; r < 4; ++r)
              if (klo + r > qrow) S[nt][r] = -1e30f;
          }
        }
        float mx0 = fmaxf(fmaxf(S[0][0], S[0][1]), fmaxf(S[0][2], S[0][3]));
        float mx1 = fmaxf(fmaxf(S[1][0], S[1][1]), fmaxf(S[1][2], S[1][3]));
        float mx2 = fmaxf(fmaxf(S[2][0], S[2][1]), fmaxf(S[2][2], S[2][3]));
        float mx3 = fmaxf(fmaxf(S[3][0], S[3][1]), fmaxf(S[3][2], S[3][3]));
        float mx = fmaxf(fmaxf(mx0, mx1), fmaxf(mx2, mx3));
        mx = fmaxf(mx, __shfl_xor(mx, 16));
        mx = fmaxf(mx, __shfl_xor(mx, 32));
        const float mn = fmaxf(m, mx);
        const float scv = exp2f(m - mn);
        m = mn;
        float rs = 0.f;
#pragma unroll
        for (int nt = 0; nt < 4; ++nt)
#pragma unroll
          for (int r = 0; r < 4; ++r) {
            const float pv = exp2f(S[nt][r] - mn);
            S[nt][r] = pv;
            rs += pv;
          }
        rs += __shfl_xor(rs, 16);
        rs += __shfl_xor(rs, 32);
        l = l * scv + rs;
#pragma unroll
        for (int nt = 0; nt < 4; ++nt) O[nt] *= scv;
        // PV with pi-permuted slots: pa lane-local (refcheck'd R17/R18)
        const int d7 = l15 & 7;
        const int vo = 4 * (lg & 1);
        __builtin_amdgcn_s_setprio(1);
#pragma unroll
        for (int kc = 0; kc < 2; ++kc) {
          short8 pa;
#pragma unroll
          for (int jj = 0; jj < 8; ++jj)
            pa[jj] = f2bf(S[2 * kc + (jj >> 2)][jj & 3]);
          const int slo = ((4 * kc + (lg >> 1)) ^ d7) << 3;
          const int shi = ((4 * kc + 2 + (lg >> 1)) ^ d7) << 3;
#pragma unroll
          for (int nt = 0; nt < 4; ++nt) {
            const short* vrow = &Vs[cb][(16 * nt + l15) * 64];
            const bh4 vlo = *reinterpret_cast<const bh4*>(&vrow[slo + vo]);
            const bh4 vhi = *reinterpret_cast<const bh4*>(&vrow[shi + vo]);
            short8 vf;
            vf[0] = vlo[0]; vf[1] = vlo[1]; vf[2] = vlo[2]; vf[3] = vlo[3];
            vf[4] = vhi[0]; vf[5] = vhi[1]; vf[6] = vhi[2]; vf[7] = vhi[3];
            O[nt] = __builtin_amdgcn_mfma_f32_16x16x32_bf16(vf, pa, O[nt], 0, 0, 0);
          }
        }
        __builtin_amdgcn_s_setprio(0);
      }
    }
  }

  // ---- publish partials directly (waves own disjoint rows; no merge) ----
  const size_t gr = (size_t)batch * T_ + qrow;
#pragma unroll
  for (int nt = 0; nt < 4; ++nt)
    *reinterpret_cast<f32x4*>(&Pg[((size_t)qh * BT_ + gr) * H_ + 16 * nt + 4 * lg]) = O[nt];
  if (lg == 0) {
    Mg[((size_t)qh * BT_ + gr) * 2 + 0] = m;
    Mg[((size_t)qh * BT_ + gr) * 2 + 1] = l;
  }
}

// ---------------------------------------------------------------------------
// combine: 4-way merge of k-quarter partials per row. 512 blocks x 256 thr,
// 2 f4-tasks/thread. exp2 algebra absorbs empty quarters (m=-1e30, l=0).
// ---------------------------------------------------------------------------
__global__ __launch_bounds__(256) void combine_kernel(
    const float* __restrict__ Pg, const float* __restrict__ Mg,
    float* __restrict__ out) {
  const int t = threadIdx.x;
#pragma unroll
  for (int k = 0; k < 2; ++k) {
    const int task = blockIdx.x * 512 + k * 256 + t;
    const int row = task >> 4;  // 0..16383
    const int c4 = task & 15;
    float Mh[4], Lh[4];
#pragma unroll
    for (int h = 0; h < 4; ++h) {
      Mh[h] = Mg[((size_t)h * BT_ + row) * 2 + 0];
      Lh[h] = Mg[((size_t)h * BT_ + row) * 2 + 1];
    }
    const float M = fmaxf(fmaxf(Mh[0], Mh[1]), fmaxf(Mh[2], Mh[3]));
    float L = 0.f;
    f32x4 o = {0.f, 0.f, 0.f, 0.f};
#pragma unroll
    for (int h = 0; h < 4; ++h) {
      const float e = exp2f(Mh[h] - M);
      L += Lh[h] * e;
      const f32x4 po =
          *reinterpret_cast<const f32x4*>(&Pg[((size_t)h * BT_ + row) * H_ + c4 * 4]);
      o += po * e;
    }
    const f32x4 res = o * (1.f / L);
    *reinterpret_cast<f32x4*>(&out[(size_t)row * H_ + c4 * 4]) = res;
  }
}

extern "C" void kernel_launch(void* const* d_in, const int* in_sizes, int n_in,
                              void* d_out, int out_size, void* d_ws, size_t ws_size,
                              hipStream_t stream) {
  const float* x = (const float*)d_in[0];
  const float* Wk = (const float*)d_in[1];
  const float* Wq = (const float*)d_in[2];
  const float* Wv = (const float*)d_in[3];
  float* out = (float*)d_out;

  short* Kp = (short*)d_ws;                  // [BT][64] bf16 (queries: x@Wk, scale*log2e folded)
  short* Qp = Kp + (size_t)BT_ * H_;         // [BT][64] bf16 (keys:    x@Wq)
  short* Vt = Qp + (size_t)BT_ * H_;         // [8][64][2048] bf16 (values^T)
  short* Wt = Vt + (size_t)BT_ * H_;         // [192][1024] bf16
  float* Pg = (float*)(Wt + 192 * C_);       // [4][BT][64] f32 partials (16MB)
  float* Mg = Pg + (size_t)4 * BT_ * H_;     // [4][BT][2]  f32 (m,l)

  hipLaunchKernelGGL(prep_w, dim3(48), dim3(256), 0, stream, Wk, Wq, Wv, Wt);
  hipLaunchKernelGGL(proj_kernel, dim3(512), dim3(256), 0, stream, x, Wt, Kp, Qp, Vt);
  hipLaunchKernelGGL(attn_kernel, dim3(512), dim3(512), 0, stream, Kp, Qp, Vt, Pg, Mg);
  hipLaunchKernelGGL(combine_kernel, dim3(512), dim3(256), 0, stream, Pg, Mg, out);
}

// Round 20
// 50.329 us; speedup vs baseline: 1.2094x; 1.0443x over previous
//
#include <hip/hip_runtime.h>
#include <cstdint>

#define B_ 8
#define T_ 2048
#define C_ 1024
#define H_ 64
#define BT_ (B_ * T_)

typedef short short8 __attribute__((ext_vector_type(8)));
typedef short bh4 __attribute__((ext_vector_type(4)));
typedef float f32x4 __attribute__((ext_vector_type(4)));

__device__ inline short f2bf(float f) {
  uint32_t u = __float_as_uint(f);
  u += 0x7fffu + ((u >> 16) & 1u);  // RNE; inputs finite
  return (short)(u >> 16);
}

// async global->LDS, 16B per lane; LDS dest = uniform base + lane*16 (HW rule)
__device__ __forceinline__ void gl_lds16(const void* g, void* l) {
  __builtin_amdgcn_global_load_lds(
      (const __attribute__((address_space(1))) unsigned int*)g,
      (__attribute__((address_space(3))) unsigned int*)l, 16, 0, 0);
}

// batched volatile asm 16B loads (un-sinkable; in-iteration lifetime only —
// the R11-proven safe pattern). Offset form: 13-bit unsigned immediate.
#define ALOADO(dst, p, off)                                        \
  asm volatile("global_load_dwordx4 %0, %1, off offset:" #off      \
               : "=v"(dst) : "v"(p) : "memory")

// ---------------------------------------------------------------------------
// prep_w: Wk/Wq/Wv [1024][64] fp32 -> Wp FRAGMENT-PACKED bf16:
// frag (c = k-chunk 0..15, nt = n-tile 0..11, f = k-half 0..1) is 1KB with
// lane (lg,l15) holding Wt[16nt+l15][64c+32f+8lg .. +7] at lane*16B.
// Folded into Wk: score scale 2^-5 AND log2(e) (softmax in log2 domain).
// ---------------------------------------------------------------------------
__global__ __launch_bounds__(256) void prep_w(
    const float* __restrict__ Wk, const float* __restrict__ Wq,
    const float* __restrict__ Wv, short* __restrict__ Wp) {
  __shared__ float wl[64][68];
  const int mat = blockIdx.x >> 4;
  const int kc = blockIdx.x & 15;
  const float* W = (mat == 0) ? Wk : (mat == 1) ? Wq : Wv;
  const float sc = (mat == 0) ? 0.03125f * 1.44269504088896f : 1.0f;
  const int t = threadIdx.x;
  const int k0 = kc * 64;
#pragma unroll
  for (int j = 0; j < 4; ++j) {
    int s = t + 256 * j;
    int kr = s >> 4, cf = s & 15;
    float4 v = *reinterpret_cast<const float4*>(&W[(size_t)(k0 + kr) * H_ + cf * 4]);
    wl[kr][cf * 4 + 0] = v.x; wl[kr][cf * 4 + 1] = v.y;
    wl[kr][cf * 4 + 2] = v.z; wl[kr][cf * 4 + 3] = v.w;
  }
  __syncthreads();
#pragma unroll
  for (int j = 0; j < 2; ++j) {
    int s = t + 256 * j;
    int n = s >> 3, g = s & 7;   // n: local col 0..63, g: 8-k group 0..7
    short8 o;
#pragma unroll
    for (int i = 0; i < 8; ++i) o[i] = f2bf(wl[8 * g + i][n] * sc);
    const int ng = mat * 64 + n;           // global col 0..191
    const int nt = ng >> 4, l15c = ng & 15;
    const int f = g >> 2, lg2 = g & 3;
    short* dst = Wp + (((size_t)(kc * 12 + nt) * 2 + f) << 9) +
                 ((lg2 << 4) + l15c) * 8;
    *reinterpret_cast<short8*>(dst) = o;
  }
}

// ---------------------------------------------------------------------------
// proj: M=32 x N=192 GEMM, 512 blocks x 256 thr (4 waves: rg=w>>1, ch=w&1).
// W is NOT staged in LDS: each wave asm-batch-loads its 12 per-step B-frags
// (contiguous 12KB in fragment-packed Wp) directly from L2 and waits
// vmcnt(2) (x gl_lds issued after W -> in-order retirement leaves exactly
// the 2 x loads outstanding). LDS = x only (16KB dbuf). Removes the 24KB/
// step W LDS round-trip + its barrier-drain share (R15: ~3100cy/period for
// ~1600cy of HBM content).
// ---------------------------------------------------------------------------
__global__ __launch_bounds__(256, 1) void proj_kernel(
    const float* __restrict__ x, const short* __restrict__ Wp,
    short* __restrict__ Kp, short* __restrict__ Qp, short* __restrict__ Vt) {
  __shared__ float xs[2][32 * 64];  // 8KB each
  const int t = threadIdx.x;
  const int w = t >> 6, lane = t & 63;
  const int l15 = lane & 15, lg = lane >> 4;
  const int rg = w >> 1, ch = w & 1;
  const int rowBase = blockIdx.x * 32;

  f32x4 acc[6];
  const f32x4 zf = {0.f, 0.f, 0.f, 0.f};
#pragma unroll
  for (int i = 0; i < 6; ++i) acc[i] = zf;

  auto stageX = [&](int buf, int k0) {
#pragma unroll
    for (int j = 0; j < 2; ++j) {
      const int seg = w * 2 + j;  // 8 segs of 4 rows
      const int r = seg * 4 + (lane >> 4);
      const float* g =
          &x[(size_t)(rowBase + r) * C_ + k0 + (((lane & 15) ^ (r & 7)) << 2)];
      gl_lds16(g, (char*)&xs[buf][0] + seg * 1024);
    }
  };

  stageX(0, 0);

#pragma unroll 1
  for (int it = 0; it < 16; ++it) {
    __syncthreads();  // drains x stage for this buffer
    const int cb = it & 1;
    // --- 12 W fragment loads (asm, batched, contiguous 12KB region) ---
    short8 bw[12];
    const short* wb0 = Wp + (((size_t)(it * 12 + 6 * ch)) << 10) + lane * 8;
    const short* wb1 = wb0 + 2048;  // +4KB
    const short* wb2 = wb0 + 4096;  // +8KB
    ALOADO(bw[0], wb0, 0);    ALOADO(bw[1], wb0, 1024);
    ALOADO(bw[2], wb0, 2048); ALOADO(bw[3], wb0, 3072);
    ALOADO(bw[4], wb1, 0);    ALOADO(bw[5], wb1, 1024);
    ALOADO(bw[6], wb1, 2048); ALOADO(bw[7], wb1, 3072);
    ALOADO(bw[8], wb2, 0);    ALOADO(bw[9], wb2, 1024);
    ALOADO(bw[10], wb2, 2048); ALOADO(bw[11], wb2, 3072);
    __builtin_amdgcn_sched_barrier(0);
    if (it < 15) stageX(cb ^ 1, (it + 1) * 64);  // x gl_lds AFTER W loads
    __builtin_amdgcn_sched_barrier(0);
    if (it < 15) {
      asm volatile("s_waitcnt vmcnt(2)" ::: "memory");  // W done; x in flight
    } else {
      asm volatile("s_waitcnt vmcnt(0)" ::: "memory");  // nothing else flying
    }
    __builtin_amdgcn_sched_barrier(0);  // rule #18: MFMA must not hoist

    // A fragments: fp32 from swizzled LDS -> bf16 (R15-identical)
    const int arow = 16 * rg + l15;
    const int x7 = arow & 7;
    const float* xrow = &xs[cb][arow * 64];
    float4 fa = *reinterpret_cast<const float4*>(xrow + (((2 * lg) ^ x7) << 2));
    float4 fb = *reinterpret_cast<const float4*>(xrow + (((2 * lg + 1) ^ x7) << 2));
    float4 fc = *reinterpret_cast<const float4*>(xrow + (((2 * lg + 8) ^ x7) << 2));
    float4 fd = *reinterpret_cast<const float4*>(xrow + (((2 * lg + 9) ^ x7) << 2));
    short8 a0, a1;
    a0[0] = f2bf(fa.x); a0[1] = f2bf(fa.y); a0[2] = f2bf(fa.z); a0[3] = f2bf(fa.w);
    a0[4] = f2bf(fb.x); a0[5] = f2bf(fb.y); a0[6] = f2bf(fb.z); a0[7] = f2bf(fb.w);
    a1[0] = f2bf(fc.x); a1[1] = f2bf(fc.y); a1[2] = f2bf(fc.z); a1[3] = f2bf(fc.w);
    a1[4] = f2bf(fd.x); a1[5] = f2bf(fd.y); a1[6] = f2bf(fd.z); a1[7] = f2bf(fd.w);
#pragma unroll
    for (int nt = 0; nt < 6; ++nt) {
      acc[nt] = __builtin_amdgcn_mfma_f32_16x16x32_bf16(a0, bw[2 * nt], acc[nt], 0, 0, 0);
      acc[nt] = __builtin_amdgcn_mfma_f32_16x16x32_bf16(a1, bw[2 * nt + 1], acc[nt], 0, 0, 0);
    }
  }

  // ---- epilogue (R15-identical) ----
  const int strip = blockIdx.x * 2 + rg;
  const int rb = strip * 16;
#pragma unroll
  for (int nt = 0; nt < 6; ++nt) {
    const int ntg = 6 * ch + nt;
    if (ntg < 8) {
      short* O = (ntg < 4) ? Kp : Qp;
      const int col = (ntg & 3) * 16 + l15;
#pragma unroll
      for (int r = 0; r < 4; ++r)
        O[(size_t)(rb + lg * 4 + r) * H_ + col] = f2bf(acc[nt][r]);
    }
  }
  __syncthreads();  // xs dead; reuse for V transpose
  if (ch == 1) {
    short* vl = reinterpret_cast<short*>(&xs[0][0]) + rg * (16 * 66);
#pragma unroll
    for (int nt = 2; nt < 6; ++nt)
#pragma unroll
      for (int r = 0; r < 4; ++r)
        vl[(lg * 4 + r) * 66 + (nt - 2) * 16 + l15] = f2bf(acc[nt][r]);
    asm volatile("s_waitcnt lgkmcnt(0)" ::: "memory");
    short8 o0, o1;
#pragma unroll
    for (int i = 0; i < 8; ++i) o0[i] = vl[i * 66 + lane];
#pragma unroll
    for (int i = 0; i < 8; ++i) o1[i] = vl[(8 + i) * 66 + lane];
    const int bb = strip >> 7, tb = (strip & 127) * 16;
    short* dst = &Vt[((size_t)bb * H_ + lane) * T_ + tb];
    *reinterpret_cast<short8*>(dst) = o0;
    *reinterpret_cast<short8*>(dst + 8) = o1;
  }
}

// ---------------------------------------------------------------------------
// attn: R19 verbatim. 512 blocks x 512 thr (8 row-groups of 16 rows).
// Block = (batch, 128-row strip, k-quarter). Partials -> Pg/Mg.
// ---------------------------------------------------------------------------
__global__ __launch_bounds__(512) void attn_kernel(
    const short* __restrict__ Kq, const short* __restrict__ Qk,
    const short* __restrict__ Vt, float* __restrict__ Pg,
    float* __restrict__ Mg) {
  __shared__ short Ks[4][64 * 64];
  __shared__ short Vs[4][64 * 64];
  const int t = threadIdx.x, w = t >> 6, lane = t & 63;
  const int l15 = lane & 15, lg = lane >> 4;
  const int batch = blockIdx.x & 7;
  const int rest = blockIdx.x >> 3;
  const int qh = rest & 3;
  const int g = rest >> 2;
  const int sidx = (g < 8) ? (15 - g) : (g - 8);
  const int rg = w;
  const short* Kb = Kq + (size_t)batch * T_ * H_;
  const short* Qb = Qk + (size_t)batch * T_ * H_;
  const short* Vb = Vt + (size_t)batch * H_ * T_;
  const f32x4 zf = {0.f, 0.f, 0.f, 0.f};
  const int k7 = l15 & 7;

  const int qbase = sidx * 128;
  const int qrow = qbase + rg * 16 + l15;
  const short8 qa0 = *reinterpret_cast<const short8*>(&Kb[(size_t)qrow * H_ + lg * 8]);
  const short8 qa1 = *reinterpret_cast<const short8*>(&Kb[(size_t)qrow * H_ + lg * 8 + 32]);
  const int ntop = 2 * sidx + 1;
  const int nlist = (ntop >= qh) ? (((ntop - qh) >> 2) + 1) : 0;
  const int np = (nlist + 1) >> 1;

  const int tp = w >> 2, kind = (w >> 1) & 1, q2 = w & 1;
  const int srow = lane >> 3;
  const int ssw = ((lane & 7) ^ srow) << 3;
  auto stage = [&](int per) {
    const int le = 2 * per + tp;
    if (le >= nlist) return;
    const int gkt = 4 * le + qh;
    const int buf = (per & 1) * 2 + tp;
    const int kbase = gkt * 64;
    if (kind == 0) {
#pragma unroll
      for (int g2 = 0; g2 < 4; ++g2) {
        const int gg = q2 * 4 + g2;
        gl_lds16(&Qb[(size_t)(kbase + gg * 8 + srow) * H_ + ssw],
                 (char*)&Ks[buf][0] + gg * 1024);
      }
    } else {
#pragma unroll
      for (int g2 = 0; g2 < 4; ++g2) {
        const int gg = q2 * 4 + g2;
        gl_lds16(&Vb[(size_t)(gg * 8 + srow) * T_ + kbase + ssw],
                 (char*)&Vs[buf][0] + gg * 1024);
      }
    }
  };

  f32x4 O[4];
#pragma unroll
  for (int i = 0; i < 4; ++i) O[i] = zf;
  float m = -1e30f, l = 0.f;

  stage(0);

#pragma unroll 1
  for (int i = 0; i < np; ++i) {
    __syncthreads();
    if (i + 1 < np) stage(i + 1);
#pragma unroll 1
    for (int tt = 0; tt < 2; ++tt) {
      const int le = 2 * i + tt;
      if (le < nlist) {
        const int gkt = 4 * le + qh;
        const int cb = (i & 1) * 2 + tt;
        const int kbase = gkt * 64;
        f32x4 S[4];
        __builtin_amdgcn_s_setprio(1);
#pragma unroll
        for (int nt = 0; nt < 4; ++nt) {
          S[nt] = zf;
          const short* krow = &Ks[cb][(16 * nt + l15) * 64];
          short8 kf0 = *reinterpret_cast<const short8*>(&krow[(lg ^ k7) << 3]);
          short8 kf1 = *reinterpret_cast<const short8*>(&krow[((4 + lg) ^ k7) << 3]);
          S[nt] = __builtin_amdgcn_mfma_f32_16x16x32_bf16(kf0, qa0, S[nt], 0, 0, 0);
          S[nt] = __builtin_amdgcn_mfma_f32_16x16x32_bf16(kf1, qa1, S[nt], 0, 0, 0);
        }
        __builtin_amdgcn_s_setprio(0);
        if (gkt >= 2 * sidx) {
#pragma unroll
          for (int nt = 0; nt < 4; ++nt) {
            const int klo = kbase + 16 * nt + 4 * lg;
#pragma unroll
            for (int r = 0; r < 4; ++r)
              if (klo + r > qrow) S[nt][r] = -1e30f;
          }
        }
        float mx0 = fmaxf(fmaxf(S[0][0], S[0][1]), fmaxf(S[0][2], S[0][3]));
        float mx1 = fmaxf(fmaxf(S[1][0], S[1][1]), fmaxf(S[1][2], S[1][3]));
        float mx2 = fmaxf(fmaxf(S[2][0], S[2][1]), fmaxf(S[2][2], S[2][3]));
        float mx3 = fmaxf(fmaxf(S[3][0], S[3][1]), fmaxf(S[3][2], S[3][3]));
        float mx = fmaxf(fmaxf(mx0, mx1), fmaxf(mx2, mx3));
        mx = fmaxf(mx, __shfl_xor(mx, 16));
        mx = fmaxf(mx, __shfl_xor(mx, 32));
        const float mn = fmaxf(m, mx);
        const float scv = exp2f(m - mn);
        m = mn;
        float rs = 0.f;
#pragma unroll
        for (int nt = 0; nt < 4; ++nt)
#pragma unroll
          for (int r = 0; r < 4; ++r) {
            const float pv = exp2f(S[nt][r] - mn);
            S[nt][r] = pv;
            rs += pv;
          }
        rs += __shfl_xor(rs, 16);
        rs += __shfl_xor(rs, 32);
        l = l * scv + rs;
#pragma unroll
        for (int nt = 0; nt < 4; ++nt) O[nt] *= scv;
        const int d7 = l15 & 7;
        const int vo = 4 * (lg & 1);
        __builtin_amdgcn_s_setprio(1);
#pragma unroll
        for (int kc = 0; kc < 2; ++kc) {
          short8 pa;
#pragma unroll
          for (int jj = 0; jj < 8; ++jj)
            pa[jj] = f2bf(S[2 * kc + (jj >> 2)][jj & 3]);
          const int slo = ((4 * kc + (lg >> 1)) ^ d7) << 3;
          const int shi = ((4 * kc + 2 + (lg >> 1)) ^ d7) << 3;
#pragma unroll
          for (int nt = 0; nt < 4; ++nt) {
            const short* vrow = &Vs[cb][(16 * nt + l15) * 64];
            const bh4 vlo = *reinterpret_cast<const bh4*>(&vrow[slo + vo]);
            const bh4 vhi = *reinterpret_cast<const bh4*>(&vrow[shi + vo]);
            short8 vf;
            vf[0] = vlo[0]; vf[1] = vlo[1]; vf[2] = vlo[2]; vf[3] = vlo[3];
            vf[4] = vhi[0]; vf[5] = vhi[1]; vf[6] = vhi[2]; vf[7] = vhi[3];
            O[nt] = __builtin_amdgcn_mfma_f32_16x16x32_bf16(vf, pa, O[nt], 0, 0, 0);
          }
        }
        __builtin_amdgcn_s_setprio(0);
      }
    }
  }

  const size_t gr = (size_t)batch * T_ + qrow;
#pragma unroll
  for (int nt = 0; nt < 4; ++nt)
    *reinterpret_cast<f32x4*>(&Pg[((size_t)qh * BT_ + gr) * H_ + 16 * nt + 4 * lg]) = O[nt];
  if (lg == 0) {
    Mg[((size_t)qh * BT_ + gr) * 2 + 0] = m;
    Mg[((size_t)qh * BT_ + gr) * 2 + 1] = l;
  }
}

// ---------------------------------------------------------------------------
// combine: 4-way merge of k-quarter partials per row (R19 verbatim).
// ---------------------------------------------------------------------------
__global__ __launch_bounds__(256) void combine_kernel(
    const float* __restrict__ Pg, const float* __restrict__ Mg,
    float* __restrict__ out) {
  const int t = threadIdx.x;
#pragma unroll
  for (int k = 0; k < 2; ++k) {
    const int task = blockIdx.x * 512 + k * 256 + t;
    const int row = task >> 4;
    const int c4 = task & 15;
    float Mh[4], Lh[4];
#pragma unroll
    for (int h = 0; h < 4; ++h) {
      Mh[h] = Mg[((size_t)h * BT_ + row) * 2 + 0];
      Lh[h] = Mg[((size_t)h * BT_ + row) * 2 + 1];
    }
    const float M = fmaxf(fmaxf(Mh[0], Mh[1]), fmaxf(Mh[2], Mh[3]));
    float L = 0.f;
    f32x4 o = {0.f, 0.f, 0.f, 0.f};
#pragma unroll
    for (int h = 0; h < 4; ++h) {
      const float e = exp2f(Mh[h] - M);
      L += Lh[h] * e;
      const f32x4 po =
          *reinterpret_cast<const f32x4*>(&Pg[((size_t)h * BT_ + row) * H_ + c4 * 4]);
      o += po * e;
    }
    const f32x4 res = o * (1.f / L);
    *reinterpret_cast<f32x4*>(&out[(size_t)row * H_ + c4 * 4]) = res;
  }
}

extern "C" void kernel_launch(void* const* d_in, const int* in_sizes, int n_in,
                              void* d_out, int out_size, void* d_ws, size_t ws_size,
                              hipStream_t stream) {
  const float* x = (const float*)d_in[0];
  const float* Wk = (const float*)d_in[1];
  const float* Wq = (const float*)d_in[2];
  const float* Wv = (const float*)d_in[3];
  float* out = (float*)d_out;

  short* Kp = (short*)d_ws;                  // [BT][64] bf16 (queries: x@Wk, scale*log2e folded)
  short* Qp = Kp + (size_t)BT_ * H_;         // [BT][64] bf16 (keys:    x@Wq)
  short* Vt = Qp + (size_t)BT_ * H_;         // [8][64][2048] bf16 (values^T)
  short* Wp = Vt + (size_t)BT_ * H_;         // [384KB] fragment-packed W bf16
  float* Pg = (float*)(Wp + 192 * C_);       // [4][BT][64] f32 partials (16MB)
  float* Mg = Pg + (size_t)4 * BT_ * H_;     // [4][BT][2]  f32 (m,l)

  hipLaunchKernelGGL(prep_w, dim3(48), dim3(256), 0, stream, Wk, Wq, Wv, Wp);
  hipLaunchKernelGGL(proj_kernel, dim3(512), dim3(256), 0, stream, x, Wp, Kp, Qp, Vt);
  hipLaunchKernelGGL(attn_kernel, dim3(512), dim3(512), 0, stream, Kp, Qp, Vt, Pg, Mg);
  hipLaunchKernelGGL(combine_kernel, dim3(512), dim3(256), 0, stream, Pg, Mg, out);
}